// Round 10
// baseline (226.291 us; speedup 1.0000x reference)
//
#include <hip/hip_runtime.h>

typedef unsigned short u16;
typedef unsigned int   u32;
typedef __attribute__((ext_vector_type(8))) short s8v;           // MFMA bf16 frag (8 bf16)
typedef __attribute__((ext_vector_type(8))) unsigned short us8;  // raw bf16x8 load
typedef __attribute__((ext_vector_type(4))) unsigned short us4;  // raw bf16x4 load
typedef __attribute__((ext_vector_type(4))) float f4v;           // MFMA acc frag

constexpr int BC  = 2;
constexpr int SL  = 4096;
constexpr int NH  = 12;
constexpr int HD  = 64;
constexpr int DM  = 768;
constexpr int WIN = 256;
constexpr int GLB = 64;
constexpr int QN  = 2304;   // q|k|v packed columns
constexpr int KCH = 32;     // global-attn key chunks (128 keys each)
constexpr float FOLD = 0.125f * 1.44269504088896f; // scale(1/sqrt(64)) * log2(e)
constexpr float NEGS = -1.0e9f;
constexpr float DEFER = 44.36f;                    // 8 / FOLD (defer-max threshold, raw units)

__device__ __forceinline__ float b2f(u16 b){ return __uint_as_float(((u32)b) << 16); }
__device__ __forceinline__ u16 f2b(float f){
  u32 u = __float_as_uint(f);
  return (u16)((u + 0x7fffu + ((u >> 16) & 1u)) >> 16);  // RNE
}
__device__ __forceinline__ float wredsum(float v){
  #pragma unroll
  for (int o = 32; o > 0; o >>= 1) v += __shfl_xor(v, o, 64);
  return v;
}
__device__ __forceinline__ float sigf(float x){ return 1.f / (1.f + __expf(-x)); }

// ---------------------------------------------------------------- fused weight pack + embed gather
__global__ void pack_embed(const float* __restrict__ Wq, const float* __restrict__ Wk,
                           const float* __restrict__ Wv, const float* __restrict__ Wo,
                           const float* __restrict__ Wp,
                           const float* __restrict__ bq, const float* __restrict__ bk,
                           const float* __restrict__ bv,
                           u16* __restrict__ wt_qkv, u16* __restrict__ wt_o,
                           u16* __restrict__ wt_p, float* __restrict__ b_qkv,
                           const int* __restrict__ ids, const float* __restrict__ emb,
                           u16* __restrict__ xb)
{
  __shared__ float tile[64][65];
  const int bid = blockIdx.x;
  const int t = threadIdx.x;
  if (bid < 720){
    const int mi = bid / 144, rest = bid % 144;
    const int kt = rest / 12, ntc = rest % 12;
    const float* src = (mi==0)?Wq:(mi==1)?Wk:(mi==2)?Wv:(mi==3)?Wo:Wp;
    u16* dst = (mi<3) ? (wt_qkv + (size_t)mi*768*768) : ((mi==3) ? wt_o : wt_p);
    const int k0 = kt*64, n0 = ntc*64;
    #pragma unroll
    for (int i=0;i<4;i++){
      const int r = (t>>4) + i*16;
      float4 v = ((const float4*)(src + (long)(k0+r)*768 + n0))[t&15];
      tile[r][(t&15)*4+0] = v.x; tile[r][(t&15)*4+1] = v.y;
      tile[r][(t&15)*4+2] = v.z; tile[r][(t&15)*4+3] = v.w;
    }
    __syncthreads();
    const int n = t & 63, kc = (t>>6)*16;
    u32* d32 = (u32*)(dst + (long)(n0+n)*768 + k0 + kc);
    #pragma unroll
    for (int i=0;i<8;i++){
      d32[i] = (u32)f2b(tile[kc+2*i][n]) | ((u32)f2b(tile[kc+2*i+1][n]) << 16);
    }
    if (bid < 9){
      const int i = bid*256 + t;
      if (i < 2304) b_qkv[i] = (i < 768) ? bq[i] : (i < 1536) ? bk[i-768] : bv[i-1536];
    }
  } else {
    int e4 = (bid-720)*256 + t;                  // 8192 rows * 192 float4
    int row = e4 / 192, d4 = e4 - row*192;
    int id = ids[row];
    float4 v = ((const float4*)(emb + (long)id*768))[d4];
    u32 p0 = (u32)f2b(v.x) | ((u32)f2b(v.y) << 16);
    u32 p1 = (u32)f2b(v.z) | ((u32)f2b(v.w) << 16);
    ((u32*)(xb + (long)row*768))[d4*2]   = p0;
    ((u32*)(xb + (long)row*768))[d4*2+1] = p1;
  }
}

__global__ void gather_hr(const int* __restrict__ hidx, const float* __restrict__ hn,
                          u16* __restrict__ hrb){
  int e = blockIdx.x*256 + threadIdx.x;          // 512 rows * 768
  if (e >= 512*768) return;
  int r = e / 768, d = e - r*768;
  int b = r >> 8;
  int idx = hidx[r];
  hrb[e] = f2b(hn[((long)(b*SL + idx))*768 + d]);
}

// ---------------------------------------------------------------- bf16 MFMA GEMM
template<int MODE, bool SWZ>
__global__ __launch_bounds__(256, 2)
void gemm_bt(const u16* __restrict__ A, const u16* __restrict__ Bt,
             const float* __restrict__ bias, const u16* __restrict__ resB,
             float* __restrict__ outF, u16* __restrict__ outB,
             int M, int N, int K, long sA, long sB, long sO)
{
  const int bz = blockIdx.z;
  A  += (long)bz * sA;
  Bt += (long)bz * sB;
  int vid = blockIdx.x + gridDim.x*blockIdx.y;
  if constexpr (SWZ){
    const int chunk = (gridDim.x*gridDim.y) >> 3;
    vid = (vid & 7)*chunk + (vid >> 3);
  }
  const int n0 = (vid % gridDim.x) * 128;
  const int m0 = (vid / gridDim.x) * 128;
  __shared__ u16 lsA[128*64];
  __shared__ u16 lsB[128*64];
  const int t = threadIdx.x;
  const int w = t >> 6, lane = t & 63;
  const int wr = w >> 1, wc = w & 1;
  const int fr = lane & 15, fq = lane >> 4;

  f4v acc[4][4];
  #pragma unroll
  for (int i=0;i<4;i++)
    #pragma unroll
    for (int j=0;j<4;j++) acc[i][j] = (f4v)0.f;

  for (int k0 = 0; k0 < K; k0 += 64){
    #pragma unroll
    for (int i=0;i<4;i++){
      int e = (w*4+i)*512 + lane*8;
      int row = e >> 6, col = e & 63;
      __builtin_amdgcn_global_load_lds(
        (const __attribute__((address_space(1))) void*)(A + (long)(m0+row)*K + (k0+col)),
        (__attribute__((address_space(3))) void*)(&lsA[(w*4+i)*512]), 16, 0, 0);
      __builtin_amdgcn_global_load_lds(
        (const __attribute__((address_space(1))) void*)(Bt + (long)(n0+row)*K + (k0+col)),
        (__attribute__((address_space(3))) void*)(&lsB[(w*4+i)*512]), 16, 0, 0);
    }
    __syncthreads();
    #pragma unroll
    for (int kk = 0; kk < 2; kk++){
      s8v af[4], bfv[4];
      #pragma unroll
      for (int mi=0;mi<4;mi++)
        af[mi] = *(const s8v*)&lsA[(wr*64 + mi*16 + fr)*64 + kk*32 + fq*8];
      #pragma unroll
      for (int ni=0;ni<4;ni++)
        bfv[ni] = *(const s8v*)&lsB[(wc*64 + ni*16 + fr)*64 + kk*32 + fq*8];
      #pragma unroll
      for (int mi=0;mi<4;mi++)
        #pragma unroll
        for (int ni=0;ni<4;ni++)
          acc[mi][ni] = __builtin_amdgcn_mfma_f32_16x16x32_bf16(af[mi], bfv[ni], acc[mi][ni], 0, 0, 0);
    }
    __syncthreads();
  }
  #pragma unroll
  for (int mi=0;mi<4;mi++){
    #pragma unroll
    for (int ni=0;ni<4;ni++){
      #pragma unroll
      for (int r=0;r<4;r++){
        int row = m0 + wr*64 + mi*16 + fq*4 + r;
        int col = n0 + wc*64 + ni*16 + fr;
        float v = acc[mi][ni][r];
        if constexpr (MODE == 0){
          v += bias[col];
          outB[(long)row*N + col] = f2b(v);
        } else if constexpr (MODE == 1){
          v += bias[col] + b2f(resB[(long)row*N + col]);
          outB[(long)row*N + col] = f2b(v);
        } else if constexpr (MODE == 2){
          v = fmaxf(v + bias[col], 0.f);
          outB[(long)row*N + col] = f2b(v);
        } else {
          (outF + bz*sO)[(long)row*N + col] = sigf(v);
        }
      }
    }
  }
}

// ---------------------------------------------------------------- banded attention, MFMA flash
// QBLK=64, 4 waves x 16 q rows, 36.4 KB LDS -> 4 blocks/CU. R8 2-barrier structure.
// V-stage u32-packed, FULL d coverage (R9 bug fixed): each lane loads 2 adjacent
// k-rows at d in [dd0,dd0+4) AND [dd0+32,dd0+36) (4x 8B) and writes 8 ds_write_b32
// of (V[k][d],V[k+1][d]) -> same V^T[d][k] u16 layout, 2x fewer LDS write instrs.
// Wave w + dq covers d in [w*8,w*8+8) and [w*8+32,w*8+40) -> all 64 d.
// q0=0 block removed (combine overwrites ctx rows 0..63 after this kernel).
__global__ __launch_bounds__(256, 4)
void attn_band_mfma(const u16* __restrict__ qkv, const float* __restrict__ mask, u16* __restrict__ ctx)
{
  const int q0 = (blockIdx.x + 1) * 64;
  const int h = blockIdx.y, b = blockIdx.z;
  const int t = threadIdx.x;
  const int w = t >> 6, lane = t & 63;
  const int fq = lane >> 4, fr = lane & 15;

  __shared__ u16 lsK[64*64];       // single buffer; row r chunk c8 holds K[r][(c8^(r&7))*8..)
  __shared__ u16 lsVT[2][64*72];   // V^T[d][k], row stride 72
  __shared__ u16 lsP[4][16*72];    // per-wave P
  __shared__ float lsM[2][64];

  const long bq = (long)b*SL*QN;
  const u16* qrow = qkv + (bq + (long)(q0 + w*16 + fr)*QN) + h*HD;
  s8v aq[2];
  aq[0] = *(const s8v*)(qrow + fq*8);
  aq[1] = *(const s8v*)(qrow + 32 + fq*8);

  // constant B-fragment: column 0 = ones -> outl col0 = sum_k P
  s8v ones_bf;
  {
    const short o = (fr == 0) ? (short)0x3F80 : (short)0;
    #pragma unroll
    for (int j=0;j<8;j++) ones_bf[j] = o;
  }

  const u16* kq = qkv + bq + DM + h*HD;
  const u16* vq = qkv + bq + 2*DM + h*HD;
  const float* mrow = mask + b*SL;

  const int ti_lo = (q0 < 320) ? ((320 - q0) >> 6) : 0;
  const int ti_hi_raw = (4352 - q0) >> 6;
  const int ti_hi = ti_hi_raw < 9 ? ti_hi_raw : 9;
  const int NTT = 1 + (ti_hi - ti_lo);
  const int kb0 = q0 - 256 + ti_lo*64;

  f4v out[4];
  f4v outl = (f4v)0.f;
  #pragma unroll
  for (int n=0;n<4;n++) out[n] = (f4v)0.f;
  float m = -3.0e38f;

  const int k2 = lane & 31, dq = lane >> 5;    // V-stage: k-pair, d-quad
  const int dd0 = w*8 + dq*4;

  us4 va0, vb0, va1, vb1;
  auto stage_issue = [&](int i, int vbuf){
    const int k0 = (i == 0) ? 0 : kb0 + (i-1)*64;
    if (t < 64) lsM[vbuf][t] = mrow[k0 + t];
    #pragma unroll
    for (int j=0;j<2;j++){
      const int r = (w*2+j)*8 + (lane>>3);
      const int d = ((lane&7) ^ (lane>>3))*8;          // pre-swizzled source col
      __builtin_amdgcn_global_load_lds(
        (const __attribute__((address_space(1))) void*)(kq + (long)(k0+r)*QN + d),
        (__attribute__((address_space(3))) void*)(&lsK[(w*2+j)*512]), 16, 0, 0);
    }
    const u16* v0 = vq + (long)(k0+2*k2)*QN;
    const u16* v1 = vq + (long)(k0+2*k2+1)*QN;
    va0 = *(const us4*)(v0 + dd0);
    vb0 = *(const us4*)(v1 + dd0);
    va1 = *(const us4*)(v0 + dd0 + 32);
    vb1 = *(const us4*)(v1 + dd0 + 32);
  };

  stage_issue(0, 0);
  int cur = 0;
  for (int i = 0; i < NTT; i++){
    const int k0 = (i == 0) ? 0 : kb0 + (i-1)*64;
    #pragma unroll
    for (int j=0;j<4;j++){
      const u32 pk0 = (u32)va0[j] | ((u32)vb0[j] << 16);
      *(u32*)&lsVT[cur][(dd0+j)*72 + 2*k2] = pk0;
      const u32 pk1 = (u32)va1[j] | ((u32)vb1[j] << 16);
      *(u32*)&lsVT[cur][(dd0+32+j)*72 + 2*k2] = pk1;
    }
    __syncthreads();                      // bar_a: K(i) DMA + V(i)/mask(i) visible

    // === S = Q K^T (raw scores) from lsK ===
    f4v s[4];
    #pragma unroll
    for (int n=0;n<4;n++) s[n] = (f4v)0.f;
    #pragma unroll
    for (int kk=0;kk<2;kk++){
      #pragma unroll
      for (int n=0;n<4;n++){
        s8v bf = *(const s8v*)&lsK[(16*n+fr)*64 + (((kk*4+fq) ^ (fr&7))<<3)];
        s[n] = __builtin_amdgcn_mfma_f32_16x16x32_bf16(aq[kk], bf, s[n], 0,0,0);
      }
    }
    __syncthreads();                      // bar_b: all waves' lsK reads done
    if (i+1 < NTT) stage_issue(i+1, cur^1);   // K-DMA overwrites lsK; V/mask -> buf^1

    // masking: wave-uniform fast path
    const bool isg = (i == 0);
    const int dlt = k0 - q0 - w*16;
    const bool maskAll = __all(lsM[cur][lane] > 0.f);
    const bool fullOK = maskAll && (isg || (dlt >= -241 && dlt <= 193));
    if (!fullOK){
      #pragma unroll
      for (int n=0;n<4;n++){
        const int kcol = 16*n + fr;
        const float mk = lsM[cur][kcol];
        #pragma unroll
        for (int r=0;r<4;r++){
          const int dd = k0 + kcol - (q0 + w*16 + fq*4 + r);
          const bool valid = (mk > 0.f) && (isg || (dd >= -WIN && dd <= WIN));
          s[n][r] = valid ? s[n][r] : NEGS;
        }
      }
    }
    // single-m online softmax, lane-local defer check
    float rmloc = fmaxf(fmaxf(fmaxf(s[0][0],s[0][1]),fmaxf(s[0][2],s[0][3])),
                        fmaxf(fmaxf(s[1][0],s[1][1]),fmaxf(s[1][2],s[1][3])));
    rmloc = fmaxf(rmloc, fmaxf(fmaxf(fmaxf(s[2][0],s[2][1]),fmaxf(s[2][2],s[2][3])),
                               fmaxf(fmaxf(s[3][0],s[3][1]),fmaxf(s[3][2],s[3][3]))));
    if (__any(rmloc > m + DEFER)){
      float rm = rmloc;
      rm = fmaxf(rm, __shfl_xor(rm, 1, 64));
      rm = fmaxf(rm, __shfl_xor(rm, 2, 64));
      rm = fmaxf(rm, __shfl_xor(rm, 4, 64));
      rm = fmaxf(rm, __shfl_xor(rm, 8, 64));
      const float mn = fmaxf(m, rm);
      const float sf = exp2f((m - mn)*FOLD);
      m = mn;
      outl *= sf;
      #pragma unroll
      for (int n=0;n<4;n++)
        #pragma unroll
        for (int r=0;r<4;r++) out[n][r] *= sf;
    }
    const float mF = m * FOLD;
    u16* lsPw = lsP[w];
    #pragma unroll
    for (int r=0;r<4;r++){
      const float p0 = exp2f(fmaf(s[0][r], FOLD, -mF));
      const float p1 = exp2f(fmaf(s[1][r], FOLD, -mF));
      const float p2 = exp2f(fmaf(s[2][r], FOLD, -mF));
      const float p3 = exp2f(fmaf(s[3][r], FOLD, -mF));
      u32 a, c;
      asm("v_cvt_pk_bf16_f32 %0, %1, %2" : "=v"(a) : "v"(p0), "v"(p1));
      asm("v_cvt_pk_bf16_f32 %0, %1, %2" : "=v"(c) : "v"(p2), "v"(p3));
      const int row = (fq*4+r)*72;
      lsPw[row + fr]      = (u16)a;
      lsPw[row + 16 + fr] = (u16)(a >> 16);
      lsPw[row + 32 + fr] = (u16)c;
      lsPw[row + 48 + fr] = (u16)(c >> 16);
    }
    // PV (+ l via reg-ones fragment)
    s8v ap[2];
    ap[0] = *(const s8v*)&lsPw[fr*72 + fq*8];
    ap[1] = *(const s8v*)&lsPw[fr*72 + 32 + fq*8];
    #pragma unroll
    for (int kk=0;kk<2;kk++){
      #pragma unroll
      for (int n=0;n<4;n++){
        s8v bv = *(const s8v*)&lsVT[cur][(16*n+fr)*72 + kk*32 + fq*8];
        out[n] = __builtin_amdgcn_mfma_f32_16x16x32_bf16(ap[kk], bv, out[n], 0,0,0);
      }
      outl = __builtin_amdgcn_mfma_f32_16x16x32_bf16(ap[kk], ones_bf, outl, 0,0,0);
    }
    cur ^= 1;
  }
  float linv[4];
  #pragma unroll
  for (int r=0;r<4;r++) linv[r] = 1.f / __shfl(outl[r], lane & 48, 64);
  u16* cb = ctx + (((long)(b*SL) + q0 + w*16 + fq*4))*DM + h*HD + fr;
  #pragma unroll
  for (int n=0;n<4;n++)
    #pragma unroll
    for (int r=0;r<4;r++)
      cb[(long)r*DM + 16*n] = f2b(out[n][r]*linv[r]);
}

// ---------------------------------------------------------------- global rows, MFMA flash partials
__global__ __launch_bounds__(256, 4)
void attn_global_part(const u16* __restrict__ qkv, const float* __restrict__ mask,
                      float* __restrict__ pout, float* __restrict__ pml)
{
  const int ck = blockIdx.x;
  const int h = blockIdx.y, b = blockIdx.z;
  const int bh = b*NH + h;
  const int t = threadIdx.x;
  const int w = t >> 6, lane = t & 63;
  const int fq = lane >> 4, fr = lane & 15;

  __shared__ u16 lsK[64*64];
  __shared__ u16 lsVT[2][64*72];
  __shared__ u16 lsP[4][16*72];
  __shared__ float lsM[2][64];

  const long bq = (long)b*SL*QN;
  const u16* qrow = qkv + (bq + (long)(w*16 + fr)*QN) + h*HD;   // q rows 0..63
  s8v aq[2];
  aq[0] = *(const s8v*)(qrow + fq*8);
  aq[1] = *(const s8v*)(qrow + 32 + fq*8);

  s8v ones_bf;
  {
    const short o = (fr == 0) ? (short)0x3F80 : (short)0;
    #pragma unroll
    for (int j=0;j<8;j++) ones_bf[j] = o;
  }

  const u16* kq = qkv + bq + DM + h*HD;
  const u16* vq = qkv + bq + 2*DM + h*HD;
  const float* mrow = mask + b*SL;

  f4v out[4];
  f4v outl = (f4v)0.f;
  #pragma unroll
  for (int n=0;n<4;n++) out[n] = (f4v)0.f;
  float m = -3.0e38f;

  const int k2 = lane & 31, dq = lane >> 5;
  const int dd0 = w*8 + dq*4;

  us4 va0, vb0, va1, vb1;
  auto stage_issue = [&](int i, int vbuf){
    const int k0 = ck*128 + i*64;
    if (t < 64) lsM[vbuf][t] = mrow[k0 + t];
    #pragma unroll
    for (int j=0;j<2;j++){
      const int r = (w*2+j)*8 + (lane>>3);
      const int d = ((lane&7) ^ (lane>>3))*8;
      __builtin_amdgcn_global_load_lds(
        (const __attribute__((address_space(1))) void*)(kq + (long)(k0+r)*QN + d),
        (__attribute__((address_space(3))) void*)(&lsK[(w*2+j)*512]), 16, 0, 0);
    }
    const u16* v0 = vq + (long)(k0+2*k2)*QN;
    const u16* v1 = vq + (long)(k0+2*k2+1)*QN;
    va0 = *(const us4*)(v0 + dd0);
    vb0 = *(const us4*)(v1 + dd0);
    va1 = *(const us4*)(v0 + dd0 + 32);
    vb1 = *(const us4*)(v1 + dd0 + 32);
  };

  stage_issue(0, 0);
  int cur = 0;
  for (int i = 0; i < 2; i++){
    #pragma unroll
    for (int j=0;j<4;j++){
      const u32 pk0 = (u32)va0[j] | ((u32)vb0[j] << 16);
      *(u32*)&lsVT[cur][(dd0+j)*72 + 2*k2] = pk0;
      const u32 pk1 = (u32)va1[j] | ((u32)vb1[j] << 16);
      *(u32*)&lsVT[cur][(dd0+32+j)*72 + 2*k2] = pk1;
    }
    __syncthreads();                      // bar_a

    f4v s[4];
    #pragma unroll
    for (int n=0;n<4;n++) s[n] = (f4v)0.f;
    #pragma unroll
    for (int kk=0;kk<2;kk++){
      #pragma unroll
      for (int n=0;n<4;n++){
        s8v bf = *(const s8v*)&lsK[(16*n+fr)*64 + (((kk*4+fq) ^ (fr&7))<<3)];
        s[n] = __builtin_amdgcn_mfma_f32_16x16x32_bf16(aq[kk], bf, s[n], 0,0,0);
      }
    }
    __syncthreads();                      // bar_b
    if (i+1 < 2) stage_issue(i+1, cur^1);

    const bool fullOK = __all(lsM[cur][lane] > 0.f);
    if (!fullOK){
      #pragma unroll
      for (int n=0;n<4;n++){
        const float mk = lsM[cur][16*n + fr];
        #pragma unroll
        for (int r=0;r<4;r++)
          s[n][r] = (mk > 0.f) ? s[n][r] : NEGS;
      }
    }
    float rmloc = fmaxf(fmaxf(fmaxf(s[0][0],s[0][1]),fmaxf(s[0][2],s[0][3])),
                        fmaxf(fmaxf(s[1][0],s[1][1]),fmaxf(s[1][2],s[1][3])));
    rmloc = fmaxf(rmloc, fmaxf(fmaxf(fmaxf(s[2][0],s[2][1]),fmaxf(s[2][2],s[2][3])),
                               fmaxf(fmaxf(s[3][0],s[3][1]),fmaxf(s[3][2],s[3][3]))));
    if (__any(rmloc > m + DEFER)){
      float rm = rmloc;
      rm = fmaxf(rm, __shfl_xor(rm, 1, 64));
      rm = fmaxf(rm, __shfl_xor(rm, 2, 64));
      rm = fmaxf(rm, __shfl_xor(rm, 4, 64));
      rm = fmaxf(rm, __shfl_xor(rm, 8, 64));
      const float mn = fmaxf(m, rm);
      const float sf = exp2f((m - mn)*FOLD);
      m = mn;
      outl *= sf;
      #pragma unroll
      for (int n=0;n<4;n++)
        #pragma unroll
        for (int r=0;r<4;r++) out[n][r] *= sf;
    }
    const float mF = m * FOLD;
    u16* lsPw = lsP[w];
    #pragma unroll
    for (int r=0;r<4;r++){
      const float p0 = exp2f(fmaf(s[0][r], FOLD, -mF));
      const float p1 = exp2f(fmaf(s[1][r], FOLD, -mF));
      const float p2 = exp2f(fmaf(s[2][r], FOLD, -mF));
      const float p3 = exp2f(fmaf(s[3][r], FOLD, -mF));
      u32 a, c;
      asm("v_cvt_pk_bf16_f32 %0, %1, %2" : "=v"(a) : "v"(p0), "v"(p1));
      asm("v_cvt_pk_bf16_f32 %0, %1, %2" : "=v"(c) : "v"(p2), "v"(p3));
      const int row = (fq*4+r)*72;
      lsPw[row + fr]      = (u16)a;
      lsPw[row + 16 + fr] = (u16)(a >> 16);
      lsPw[row + 32 + fr] = (u16)c;
      lsPw[row + 48 + fr] = (u16)(c >> 16);
    }
    s8v ap[2];
    ap[0] = *(const s8v*)&lsPw[fr*72 + fq*8];
    ap[1] = *(const s8v*)&lsPw[fr*72 + 32 + fq*8];
    #pragma unroll
    for (int kk=0;kk<2;kk++){
      #pragma unroll
      for (int n=0;n<4;n++){
        s8v bv = *(const s8v*)&lsVT[cur][(16*n+fr)*72 + kk*32 + fq*8];
        out[n] = __builtin_amdgcn_mfma_f32_16x16x32_bf16(ap[kk], bv, out[n], 0,0,0);
      }
      outl = __builtin_amdgcn_mfma_f32_16x16x32_bf16(ap[kk], ones_bf, outl, 0,0,0);
    }
    cur ^= 1;
  }
  float* pob = pout + ((long)(ck*BC*NH + bh))*64*64;
  #pragma unroll
  for (int n=0;n<4;n++)
    #pragma unroll
    for (int r=0;r<4;r++)
      pob[(w*16 + fq*4 + r)*64 + 16*n + fr] = out[n][r];
  if (fr == 0){
    float* pmb = pml + ((long)(ck*BC*NH + bh))*128;
    #pragma unroll
    for (int r=0;r<4;r++){
      pmb[(w*16 + fq*4 + r)*2 + 0] = m * FOLD;      // log2-domain max
      pmb[(w*16 + fq*4 + r)*2 + 1] = outl[r];       // l (reg-ones MFMA column)
    }
  }
}

__global__ __launch_bounds__(256, 2)
void attn_global_combine(const float* __restrict__ pout, const float* __restrict__ pml,
                         u16* __restrict__ ctx)
{
  const int bh = blockIdx.x;
  const int b = bh / NH, h = bh % NH;
  const int t = threadIdx.x;
  __shared__ float wgt[KCH][64];
  __shared__ float rl[64];
  if (t < 64){
    float mc[KCH], lc[KCH];
    #pragma unroll
    for (int c = 0; c < KCH; c++){
      const float* pmb = pml + ((long)(c*BC*NH + bh))*128 + t*2;
      mc[c] = pmb[0]; lc[c] = pmb[1];
    }
    float M = mc[0];
    #pragma unroll
    for (int c = 1; c < KCH; c++) M = fmaxf(M, mc[c]);
    float L = 0.f;
    #pragma unroll
    for (int c = 0; c < KCH; c++){
      const float wv = exp2f(mc[c] - M);
      wgt[c][t] = wv;
      L += lc[c]*wv;
    }
    rl[t] = 1.f/L;
  }
  __syncthreads();
  const int row = t >> 2, dseg = t & 3;
  float acc[16];
  #pragma unroll
  for (int i=0;i<16;i++) acc[i] = 0.f;
  for (int c = 0; c < KCH; c++){
    const float wv = wgt[c][row];
    const float4* pb = (const float4*)(pout + ((long)(c*BC*NH + bh)*64 + row)*64 + dseg*16);
    #pragma unroll
    for (int i = 0; i < 4; i++){
      float4 v = pb[i];
      acc[i*4+0] += v.x*wv; acc[i*4+1] += v.y*wv;
      acc[i*4+2] += v.z*wv; acc[i*4+3] += v.w*wv;
    }
  }
  u16* cr = ctx + ((long)(b*SL + row))*DM + h*HD + dseg*16;
  const float r = rl[row];
  #pragma unroll
  for (int i = 0; i < 16; i += 2){
    u32 pk = (u32)f2b(acc[i]*r) | ((u32)f2b(acc[i+1]*r) << 16);
    *(u32*)(cr + i) = pk;
  }
}

// ---------------------------------------------------------------- LayerNorm + ans/span heads (bf16 h input)
__global__ __launch_bounds__(384, 2)
void ln_heads(const u16* __restrict__ hb, const float* __restrict__ gamma, const float* __restrict__ beta,
              const float* __restrict__ Wa, const float* __restrict__ ba,
              const float* __restrict__ Wsp, const float* __restrict__ bsp,
              float* __restrict__ hn, float* __restrict__ ans, float* __restrict__ span)
{
  const int r = blockIdx.x;
  const int t = threadIdx.x, lane = t & 63, w = t >> 6;   // w in 0..5
  __shared__ float red[12];
  __shared__ float dred[6][5];
  const u32 pk = ((const u32*)(hb + (long)r*DM))[t];
  const float v0 = b2f((u16)(pk & 0xffff));
  const float v1 = b2f((u16)(pk >> 16));
  float sum = wredsum(v0 + v1);
  float sq  = wredsum(v0*v0 + v1*v1);
  if (lane == 0){ red[w] = sum; red[6+w] = sq; }
  __syncthreads();
  float mu = 0.f, msq = 0.f;
  #pragma unroll
  for (int i=0;i<6;i++){ mu += red[i]; msq += red[6+i]; }
  mu *= (1.f/768.f); msq *= (1.f/768.f);
  const float rstd = rsqrtf(msq - mu*mu + 1e-5f);
  const int i0 = 2*t, i1 = 2*t+1;
  const float y0 = (v0 - mu)*rstd*gamma[i0] + beta[i0];
  const float y1 = (v1 - mu)*rstd*gamma[i1] + beta[i1];
  ((float2*)(hn + (long)r*DM))[t] = make_float2(y0, y1);
  float pa0 = y0*Wa[i0*3+0] + y1*Wa[i1*3+0];
  float pa1 = y0*Wa[i0*3+1] + y1*Wa[i1*3+1];
  float pa2 = y0*Wa[i0*3+2] + y1*Wa[i1*3+2];
  float ps0 = y0*Wsp[i0*2+0] + y1*Wsp[i1*2+0];
  float ps1 = y0*Wsp[i0*2+1] + y1*Wsp[i1*2+1];
  pa0 = wredsum(pa0); pa1 = wredsum(pa1); pa2 = wredsum(pa2);
  ps0 = wredsum(ps0); ps1 = wredsum(ps1);
  if (lane == 0){ dred[w][0]=pa0; dred[w][1]=pa1; dred[w][2]=pa2; dred[w][3]=ps0; dred[w][4]=ps1; }
  __syncthreads();
  if (t == 0){
    float A0=0,A1=0,A2=0,S0=0,S1=0;
    #pragma unroll
    for (int i=0;i<6;i++){ A0+=dred[i][0]; A1+=dred[i][1]; A2+=dred[i][2]; S0+=dred[i][3]; S1+=dred[i][4]; }
    ans[(long)r*3+0]  = sigf(A0 + ba[0]);
    ans[(long)r*3+1]  = sigf(A1 + ba[1]);
    ans[(long)r*3+2]  = sigf(A2 + ba[2]);
    span[(long)r*2+0] = sigf(S0 + bsp[0]);
    span[(long)r*2+1] = sigf(S1 + bsp[1]);
  }
}

// ---------------------------------------------------------------- launch
extern "C" void kernel_launch(void* const* d_in, const int* in_sizes, int n_in,
                              void* d_out, int out_size, void* d_ws, size_t ws_size,
                              hipStream_t stream)
{
  const int*   input_ids = (const int*)  d_in[0];
  const float* attn_mask = (const float*)d_in[1];
  const int*   html_idx  = (const int*)  d_in[2];
  const float* embed     = (const float*)d_in[3];
  const float* Wq = (const float*)d_in[4];  const float* bq = (const float*)d_in[5];
  const float* Wk = (const float*)d_in[6];  const float* bk = (const float*)d_in[7];
  const float* Wv = (const float*)d_in[8];  const float* bv = (const float*)d_in[9];
  const float* Wo = (const float*)d_in[10]; const float* bo = (const float*)d_in[11];
  const float* gamma = (const float*)d_in[12]; const float* beta = (const float*)d_in[13];
  const float* Wp = (const float*)d_in[14]; const float* bp = (const float*)d_in[15];
  const float* Wa = (const float*)d_in[16]; const float* ba = (const float*)d_in[17];
  const float* Wsp = (const float*)d_in[18]; const float* bsp = (const float*)d_in[19];

  char* ws = (char*)d_ws;
  size_t off = 0;
  auto take = [&](size_t bytes)->char*{
    char* p = ws + off; off += (bytes + 255) & ~(size_t)255; return p;
  };
  u16*   x_b    = (u16*)  take((size_t)8192*768*2);
  u16*   wt_qkv = (u16*)  take((size_t)2304*768*2);
  u16*   wt_o   = (u16*)  take((size_t)768*768*2);
  u16*   wt_p   = (u16*)  take((size_t)768*768*2);
  float* b_qkv  = (float*)take(2304*4);
  u16*   qkv_b  = (u16*)  take((size_t)8192*2304*2);
  u16*   ctx_b  = (u16*)  take((size_t)8192*768*2);
  u16*   h_b    = (u16*)  take((size_t)8192*768*2);
  u16*   hr_b   = (u16*)  take((size_t)512*768*2);
  u16*   t_b    = (u16*)  take((size_t)512*768*2);
  float* pout   = (float*)take((size_t)KCH*BC*NH*64*64*4);
  float* pml    = (float*)take((size_t)KCH*BC*NH*128*4);

  float* out_hn   = (float*)d_out;
  float* out_ans  = out_hn  + (size_t)8192*768;
  float* out_span = out_ans + (size_t)8192*3;
  float* out_cond = out_span + (size_t)8192*2;

  pack_embed<<<6864, 256, 0, stream>>>(Wq, Wk, Wv, Wo, Wp, bq, bk, bv,
                                       wt_qkv, wt_o, wt_p, b_qkv,
                                       input_ids, embed, x_b);

  gemm_bt<0,true><<<dim3(18,64,1), 256, 0, stream>>>(x_b, wt_qkv, b_qkv, nullptr,
                                                nullptr, qkv_b, 8192, 2304, 768, 0,0,0);
  attn_band_mfma<<<dim3(63,12,2), 256, 0, stream>>>(qkv_b, attn_mask, ctx_b);
  attn_global_part<<<dim3(KCH,12,2), 256, 0, stream>>>(qkv_b, attn_mask, pout, pml);
  attn_global_combine<<<BC*NH, 256, 0, stream>>>(pout, pml, ctx_b);
  gemm_bt<1,true><<<dim3(6,64,1), 256, 0, stream>>>(ctx_b, wt_o, bo, x_b,
                                               nullptr, h_b, 8192, 768, 768, 0,0,0);
  ln_heads<<<8192, 384, 0, stream>>>(h_b, gamma, beta, Wa, ba, Wsp, bsp,
                                     out_hn, out_ans, out_span);
  gather_hr<<<1536, 256, 0, stream>>>(html_idx, out_hn, hr_b);
  gemm_bt<2,false><<<dim3(6,4,1), 256, 0, stream>>>(hr_b, wt_p, bp, nullptr,
                                              nullptr, t_b, 512, 768, 768, 0,0,0);
  gemm_bt<3,false><<<dim3(2,2,2), 256, 0, stream>>>(t_b, hr_b, nullptr, nullptr,
                                              out_cond, nullptr, 256, 256, 768,
                                              (long)256*768, (long)256*768, (long)256*256);
}

// Round 11
// 223.348 us; speedup vs baseline: 1.0132x; 1.0132x over previous
//
#include <hip/hip_runtime.h>

typedef unsigned short u16;
typedef unsigned int   u32;
typedef unsigned long long u64;
typedef __attribute__((ext_vector_type(8))) short s8v;           // MFMA bf16 frag (8 bf16)
typedef __attribute__((ext_vector_type(8))) unsigned short us8;  // raw bf16x8 load
typedef __attribute__((ext_vector_type(4))) unsigned short us4;  // raw bf16x4 load
typedef __attribute__((ext_vector_type(4))) float f4v;           // MFMA acc frag

constexpr int BC  = 2;
constexpr int SL  = 4096;
constexpr int NH  = 12;
constexpr int HD  = 64;
constexpr int DM  = 768;
constexpr int WIN = 256;
constexpr int GLB = 64;
constexpr int QN  = 2304;   // q|k|v packed columns
constexpr int KCH = 32;     // global-attn key chunks (128 keys each)
constexpr float FOLD = 0.125f * 1.44269504088896f; // scale(1/sqrt(64)) * log2(e)
constexpr float NEGS = -1.0e9f;
constexpr float DEFER = 44.36f;                    // 8 / FOLD (defer-max threshold, raw units)

__device__ __forceinline__ float b2f(u16 b){ return __uint_as_float(((u32)b) << 16); }
__device__ __forceinline__ u16 f2b(float f){
  u32 u = __float_as_uint(f);
  return (u16)((u + 0x7fffu + ((u >> 16) & 1u)) >> 16);  // RNE
}
__device__ __forceinline__ float wredsum(float v){
  #pragma unroll
  for (int o = 32; o > 0; o >>= 1) v += __shfl_xor(v, o, 64);
  return v;
}
__device__ __forceinline__ float sigf(float x){ return 1.f / (1.f + __expf(-x)); }

// ---------------------------------------------------------------- fused weight pack + embed gather
__global__ void pack_embed(const float* __restrict__ Wq, const float* __restrict__ Wk,
                           const float* __restrict__ Wv, const float* __restrict__ Wo,
                           const float* __restrict__ Wp,
                           const float* __restrict__ bq, const float* __restrict__ bk,
                           const float* __restrict__ bv,
                           u16* __restrict__ wt_qkv, u16* __restrict__ wt_o,
                           u16* __restrict__ wt_p, float* __restrict__ b_qkv,
                           const int* __restrict__ ids, const float* __restrict__ emb,
                           u16* __restrict__ xb)
{
  __shared__ float tile[64][65];
  const int bid = blockIdx.x;
  const int t = threadIdx.x;
  if (bid < 720){
    const int mi = bid / 144, rest = bid % 144;
    const int kt = rest / 12, ntc = rest % 12;
    const float* src = (mi==0)?Wq:(mi==1)?Wk:(mi==2)?Wv:(mi==3)?Wo:Wp;
    u16* dst = (mi<3) ? (wt_qkv + (size_t)mi*768*768) : ((mi==3) ? wt_o : wt_p);
    const int k0 = kt*64, n0 = ntc*64;
    #pragma unroll
    for (int i=0;i<4;i++){
      const int r = (t>>4) + i*16;
      float4 v = ((const float4*)(src + (long)(k0+r)*768 + n0))[t&15];
      tile[r][(t&15)*4+0] = v.x; tile[r][(t&15)*4+1] = v.y;
      tile[r][(t&15)*4+2] = v.z; tile[r][(t&15)*4+3] = v.w;
    }
    __syncthreads();
    const int n = t & 63, kc = (t>>6)*16;
    u32* d32 = (u32*)(dst + (long)(n0+n)*768 + k0 + kc);
    #pragma unroll
    for (int i=0;i<8;i++){
      d32[i] = (u32)f2b(tile[kc+2*i][n]) | ((u32)f2b(tile[kc+2*i+1][n]) << 16);
    }
    if (bid < 9){
      const int i = bid*256 + t;
      if (i < 2304) b_qkv[i] = (i < 768) ? bq[i] : (i < 1536) ? bk[i-768] : bv[i-1536];
    }
  } else {
    int e4 = (bid-720)*256 + t;                  // 8192 rows * 192 float4
    int row = e4 / 192, d4 = e4 - row*192;
    int id = ids[row];
    float4 v = ((const float4*)(emb + (long)id*768))[d4];
    u32 p0 = (u32)f2b(v.x) | ((u32)f2b(v.y) << 16);
    u32 p1 = (u32)f2b(v.z) | ((u32)f2b(v.w) << 16);
    ((u32*)(xb + (long)row*768))[d4*2]   = p0;
    ((u32*)(xb + (long)row*768))[d4*2+1] = p1;
  }
}

__global__ void gather_hr(const int* __restrict__ hidx, const float* __restrict__ hn,
                          u16* __restrict__ hrb){
  int e = blockIdx.x*256 + threadIdx.x;          // 512 rows * 768
  if (e >= 512*768) return;
  int r = e / 768, d = e - r*768;
  int b = r >> 8;
  int idx = hidx[r];
  hrb[e] = f2b(hn[((long)(b*SL + idx))*768 + d]);
}

// ---------------------------------------------------------------- bf16 MFMA GEMM
template<int MODE, bool SWZ>
__global__ __launch_bounds__(256, 2)
void gemm_bt(const u16* __restrict__ A, const u16* __restrict__ Bt,
             const float* __restrict__ bias, const u16* __restrict__ resB,
             float* __restrict__ outF, u16* __restrict__ outB,
             int M, int N, int K, long sA, long sB, long sO)
{
  const int bz = blockIdx.z;
  A  += (long)bz * sA;
  Bt += (long)bz * sB;
  int vid = blockIdx.x + gridDim.x*blockIdx.y;
  if constexpr (SWZ){
    const int chunk = (gridDim.x*gridDim.y) >> 3;
    vid = (vid & 7)*chunk + (vid >> 3);
  }
  const int n0 = (vid % gridDim.x) * 128;
  const int m0 = (vid / gridDim.x) * 128;
  __shared__ u16 lsA[128*64];
  __shared__ u16 lsB[128*64];
  const int t = threadIdx.x;
  const int w = t >> 6, lane = t & 63;
  const int wr = w >> 1, wc = w & 1;
  const int fr = lane & 15, fq = lane >> 4;

  f4v acc[4][4];
  #pragma unroll
  for (int i=0;i<4;i++)
    #pragma unroll
    for (int j=0;j<4;j++) acc[i][j] = (f4v)0.f;

  for (int k0 = 0; k0 < K; k0 += 64){
    #pragma unroll
    for (int i=0;i<4;i++){
      int e = (w*4+i)*512 + lane*8;
      int row = e >> 6, col = e & 63;
      __builtin_amdgcn_global_load_lds(
        (const __attribute__((address_space(1))) void*)(A + (long)(m0+row)*K + (k0+col)),
        (__attribute__((address_space(3))) void*)(&lsA[(w*4+i)*512]), 16, 0, 0);
      __builtin_amdgcn_global_load_lds(
        (const __attribute__((address_space(1))) void*)(Bt + (long)(n0+row)*K + (k0+col)),
        (__attribute__((address_space(3))) void*)(&lsB[(w*4+i)*512]), 16, 0, 0);
    }
    __syncthreads();
    #pragma unroll
    for (int kk = 0; kk < 2; kk++){
      s8v af[4], bfv[4];
      #pragma unroll
      for (int mi=0;mi<4;mi++)
        af[mi] = *(const s8v*)&lsA[(wr*64 + mi*16 + fr)*64 + kk*32 + fq*8];
      #pragma unroll
      for (int ni=0;ni<4;ni++)
        bfv[ni] = *(const s8v*)&lsB[(wc*64 + ni*16 + fr)*64 + kk*32 + fq*8];
      #pragma unroll
      for (int mi=0;mi<4;mi++)
        #pragma unroll
        for (int ni=0;ni<4;ni++)
          acc[mi][ni] = __builtin_amdgcn_mfma_f32_16x16x32_bf16(af[mi], bfv[ni], acc[mi][ni], 0, 0, 0);
    }
    __syncthreads();
  }
  #pragma unroll
  for (int mi=0;mi<4;mi++){
    #pragma unroll
    for (int ni=0;ni<4;ni++){
      #pragma unroll
      for (int r=0;r<4;r++){
        int row = m0 + wr*64 + mi*16 + fq*4 + r;
        int col = n0 + wc*64 + ni*16 + fr;
        float v = acc[mi][ni][r];
        if constexpr (MODE == 0){
          v += bias[col];
          outB[(long)row*N + col] = f2b(v);
        } else if constexpr (MODE == 1){
          v += bias[col] + b2f(resB[(long)row*N + col]);
          outB[(long)row*N + col] = f2b(v);
        } else if constexpr (MODE == 2){
          v = fmaxf(v + bias[col], 0.f);
          outB[(long)row*N + col] = f2b(v);
        } else {
          (outF + bz*sO)[(long)row*N + col] = sigf(v);
        }
      }
    }
  }
}

// ---------------------------------------------------------------- banded attention, MFMA flash, SWAPPED QK^T
// QBLK=64, 4 waves x 16 q rows, 26 KB LDS. Same 2-barrier hazard structure as R8.
// Swapped QK^T: s[n] = mfma(Kfrag, Qfrag) -> s[n][r] = S[q=fr][k = 16n+4fq+r], so
// softmax P is lane-local per query: P->bf16 via cvt_pk entirely IN REGISTER, and
// PV's A-fragment is assembled with zero LDS (lsP deleted). Correctness hinges on
// V^T being stored with permuted k-columns: column c = 32kk+8fq+4a+r holds
// V[k'=16(2kk+a)+4fq+r], so PV slot (kk,fq,j=4a+r) multiplies P[q][k']*V[k'][d].
// Mask via __ballot (lsM deleted); m is wave-uniform (exact: same m in P and l).
// Output layout / l(ones-MFMA) / C-write identical to R8.
__global__ __launch_bounds__(256, 4)
void attn_band_mfma(const u16* __restrict__ qkv, const float* __restrict__ mask, u16* __restrict__ ctx)
{
  const int q0 = (blockIdx.x + 1) * 64;
  const int h = blockIdx.y, b = blockIdx.z;
  const int t = threadIdx.x;
  const int w = t >> 6, lane = t & 63;
  const int fq = lane >> 4, fr = lane & 15;

  __shared__ u16 lsK[64*64];       // single buffer; row r chunk c8 holds K[r][(c8^(r&7))*8..)
  __shared__ u16 lsVT[2][64*72];   // V^T[d][k-permuted], row stride 72

  const long bq = (long)b*SL*QN;
  const u16* qrow = qkv + (bq + (long)(q0 + w*16 + fr)*QN) + h*HD;
  s8v aq[2];
  aq[0] = *(const s8v*)(qrow + fq*8);
  aq[1] = *(const s8v*)(qrow + 32 + fq*8);

  // constant B-fragment: d-row 0 = ones -> outl col0 = sum_k P
  s8v ones_bf;
  {
    const short o = (fr == 0) ? (short)0x3F80 : (short)0;
    #pragma unroll
    for (int j=0;j<8;j++) ones_bf[j] = o;
  }

  const u16* kq = qkv + bq + DM + h*HD;
  const u16* vq = qkv + bq + 2*DM + h*HD;
  const float* mrow = mask + b*SL;

  const int ti_lo = (q0 < 320) ? ((320 - q0) >> 6) : 0;
  const int ti_hi_raw = (4352 - q0) >> 6;
  const int ti_hi = ti_hi_raw < 9 ? ti_hi_raw : 9;
  const int NTT = 1 + (ti_hi - ti_lo);
  const int kb0 = q0 - 256 + ti_lo*64;

  f4v out[4];
  f4v outl = (f4v)0.f;
  #pragma unroll
  for (int n=0;n<4;n++) out[n] = (f4v)0.f;
  float m = -3.0e38f;             // wave-uniform running max (raw-score units)

  const int k2 = lane & 31, dq = lane >> 5;    // V-stage: k-pair, d-quad
  const int dd0 = w*8 + dq*4;
  // permuted column for k-pair (2*k2, 2*k2+1): kv=2*k2
  const int kv = 2*k2;
  const int cperm = (((kv>>4)>>1)<<5) + (((kv>>2)&3)<<3) + (((kv>>4)&1)<<2) + (kv&3);

  us4 va0, vb0, va1, vb1;
  float mval;
  auto stage_issue = [&](int i){
    const int k0 = (i == 0) ? 0 : kb0 + (i-1)*64;
    mval = mrow[k0 + lane];
    #pragma unroll
    for (int j=0;j<2;j++){
      const int r = (w*2+j)*8 + (lane>>3);
      const int d = ((lane&7) ^ (lane>>3))*8;          // pre-swizzled source col
      __builtin_amdgcn_global_load_lds(
        (const __attribute__((address_space(1))) void*)(kq + (long)(k0+r)*QN + d),
        (__attribute__((address_space(3))) void*)(&lsK[(w*2+j)*512]), 16, 0, 0);
    }
    const u16* v0 = vq + (long)(k0+kv)*QN;
    const u16* v1 = vq + (long)(k0+kv+1)*QN;
    va0 = *(const us4*)(v0 + dd0);
    vb0 = *(const us4*)(v1 + dd0);
    va1 = *(const us4*)(v0 + dd0 + 32);
    vb1 = *(const us4*)(v1 + dd0 + 32);
  };

  stage_issue(0);
  int cur = 0;
  for (int i = 0; i < NTT; i++){
    const int k0 = (i == 0) ? 0 : kb0 + (i-1)*64;
    #pragma unroll
    for (int j=0;j<4;j++){
      const u32 pk0 = (u32)va0[j] | ((u32)vb0[j] << 16);
      *(u32*)&lsVT[cur][(dd0+j)*72 + cperm] = pk0;
      const u32 pk1 = (u32)va1[j] | ((u32)vb1[j] << 16);
      *(u32*)&lsVT[cur][(dd0+32+j)*72 + cperm] = pk1;
    }
    __syncthreads();                      // bar_a: K(i) DMA + V(i) visible

    // === S^T tile: s[n] = K[16n..16n+16) x Q^T  (lane: q=fr, k=16n+4fq+r) ===
    f4v s[4];
    #pragma unroll
    for (int n=0;n<4;n++) s[n] = (f4v)0.f;
    #pragma unroll
    for (int kk=0;kk<2;kk++){
      #pragma unroll
      for (int n=0;n<4;n++){
        s8v bf = *(const s8v*)&lsK[(16*n+fr)*64 + (((kk*4+fq) ^ (fr&7))<<3)];
        s[n] = __builtin_amdgcn_mfma_f32_16x16x32_bf16(bf, aq[kk], s[n], 0,0,0);
      }
    }
    __syncthreads();                      // bar_b: all waves' lsK reads done
    const u64 mkb = __ballot(mval > 0.f); // mask bits for THIS tile (loaded at stage(i))
    if (i+1 < NTT) stage_issue(i+1);      // K-DMA overwrites lsK; V/mask regs -> next

    // masking (lane: q = q0+w*16+fr, k = k0+16n+4fq+r)
    const bool isg = (i == 0);
    const int dlt = k0 - q0 - w*16;
    const bool fullOK = (~mkb == 0ull) && (isg || (dlt >= -241 && dlt <= 193));
    if (!fullOK){
      const int base = k0 + 4*fq - (q0 + w*16 + fr);
      #pragma unroll
      for (int n=0;n<4;n++){
        #pragma unroll
        for (int r=0;r<4;r++){
          const bool mb = (mkb >> (16*n + 4*fq + r)) & 1ull;
          const int dd = base + 16*n + r;
          const bool valid = mb && (isg || (dd >= -WIN && dd <= WIN));
          s[n][r] = valid ? s[n][r] : NEGS;
        }
      }
    }
    // wave-uniform online max with defer (reduce only on demand)
    float rmloc = fmaxf(fmaxf(fmaxf(s[0][0],s[0][1]),fmaxf(s[0][2],s[0][3])),
                        fmaxf(fmaxf(s[1][0],s[1][1]),fmaxf(s[1][2],s[1][3])));
    rmloc = fmaxf(rmloc, fmaxf(fmaxf(fmaxf(s[2][0],s[2][1]),fmaxf(s[2][2],s[2][3])),
                               fmaxf(fmaxf(s[3][0],s[3][1]),fmaxf(s[3][2],s[3][3]))));
    if (__any(rmloc > m + DEFER)){
      float rm = rmloc;
      rm = fmaxf(rm, __shfl_xor(rm, 1, 64));
      rm = fmaxf(rm, __shfl_xor(rm, 2, 64));
      rm = fmaxf(rm, __shfl_xor(rm, 4, 64));
      rm = fmaxf(rm, __shfl_xor(rm, 8, 64));
      rm = fmaxf(rm, __shfl_xor(rm, 16, 64));
      rm = fmaxf(rm, __shfl_xor(rm, 32, 64));
      const float mn = fmaxf(m, rm);
      const float sf = exp2f((m - mn)*FOLD);
      m = mn;
      outl *= sf;
      #pragma unroll
      for (int n=0;n<4;n++)
        #pragma unroll
        for (int r=0;r<4;r++) out[n][r] *= sf;
    }
    const float mF = m * FOLD;
    // P in-register: p[n][r] = exp2(s*FOLD - mF); assemble PV A-frags via cvt_pk.
    // ap[kk] slots j=4a+r hold p[2kk+a][r]  (matches V^T column permutation).
    float p00 = exp2f(fmaf(s[0][0], FOLD, -mF)), p01 = exp2f(fmaf(s[0][1], FOLD, -mF));
    float p02 = exp2f(fmaf(s[0][2], FOLD, -mF)), p03 = exp2f(fmaf(s[0][3], FOLD, -mF));
    float p10 = exp2f(fmaf(s[1][0], FOLD, -mF)), p11 = exp2f(fmaf(s[1][1], FOLD, -mF));
    float p12 = exp2f(fmaf(s[1][2], FOLD, -mF)), p13 = exp2f(fmaf(s[1][3], FOLD, -mF));
    float p20 = exp2f(fmaf(s[2][0], FOLD, -mF)), p21 = exp2f(fmaf(s[2][1], FOLD, -mF));
    float p22 = exp2f(fmaf(s[2][2], FOLD, -mF)), p23 = exp2f(fmaf(s[2][3], FOLD, -mF));
    float p30 = exp2f(fmaf(s[3][0], FOLD, -mF)), p31 = exp2f(fmaf(s[3][1], FOLD, -mF));
    float p32 = exp2f(fmaf(s[3][2], FOLD, -mF)), p33 = exp2f(fmaf(s[3][3], FOLD, -mF));
    u32 c0,c1,c2,c3,c4,c5,c6,c7;
    asm("v_cvt_pk_bf16_f32 %0, %1, %2" : "=v"(c0) : "v"(p00), "v"(p01));
    asm("v_cvt_pk_bf16_f32 %0, %1, %2" : "=v"(c1) : "v"(p02), "v"(p03));
    asm("v_cvt_pk_bf16_f32 %0, %1, %2" : "=v"(c2) : "v"(p10), "v"(p11));
    asm("v_cvt_pk_bf16_f32 %0, %1, %2" : "=v"(c3) : "v"(p12), "v"(p13));
    asm("v_cvt_pk_bf16_f32 %0, %1, %2" : "=v"(c4) : "v"(p20), "v"(p21));
    asm("v_cvt_pk_bf16_f32 %0, %1, %2" : "=v"(c5) : "v"(p22), "v"(p23));
    asm("v_cvt_pk_bf16_f32 %0, %1, %2" : "=v"(c6) : "v"(p30), "v"(p31));
    asm("v_cvt_pk_bf16_f32 %0, %1, %2" : "=v"(c7) : "v"(p32), "v"(p33));
    s8v ap0, ap1;
    { u32* u = (u32*)&ap0; u[0]=c0; u[1]=c1; u[2]=c2; u[3]=c3; }
    { u32* u = (u32*)&ap1; u[0]=c4; u[1]=c5; u[2]=c6; u[3]=c7; }
    // PV (+ l via reg-ones fragment)
    #pragma unroll
    for (int n=0;n<4;n++){
      s8v bv0 = *(const s8v*)&lsVT[cur][(16*n+fr)*72 + fq*8];
      out[n] = __builtin_amdgcn_mfma_f32_16x16x32_bf16(ap0, bv0, out[n], 0,0,0);
      s8v bv1 = *(const s8v*)&lsVT[cur][(16*n+fr)*72 + 32 + fq*8];
      out[n] = __builtin_amdgcn_mfma_f32_16x16x32_bf16(ap1, bv1, out[n], 0,0,0);
    }
    outl = __builtin_amdgcn_mfma_f32_16x16x32_bf16(ap0, ones_bf, outl, 0,0,0);
    outl = __builtin_amdgcn_mfma_f32_16x16x32_bf16(ap1, ones_bf, outl, 0,0,0);
    cur ^= 1;
  }
  float linv[4];
  #pragma unroll
  for (int r=0;r<4;r++) linv[r] = 1.f / __shfl(outl[r], lane & 48, 64);
  u16* cb = ctx + (((long)(b*SL) + q0 + w*16 + fq*4))*DM + h*HD + fr;
  #pragma unroll
  for (int n=0;n<4;n++)
    #pragma unroll
    for (int r=0;r<4;r++)
      cb[(long)r*DM + 16*n] = f2b(out[n][r]*linv[r]);
}

// ---------------------------------------------------------------- global rows, MFMA flash partials (R10-proven)
__global__ __launch_bounds__(256, 4)
void attn_global_part(const u16* __restrict__ qkv, const float* __restrict__ mask,
                      float* __restrict__ pout, float* __restrict__ pml)
{
  const int ck = blockIdx.x;
  const int h = blockIdx.y, b = blockIdx.z;
  const int bh = b*NH + h;
  const int t = threadIdx.x;
  const int w = t >> 6, lane = t & 63;
  const int fq = lane >> 4, fr = lane & 15;

  __shared__ u16 lsK[64*64];
  __shared__ u16 lsVT[2][64*72];
  __shared__ u16 lsP[4][16*72];
  __shared__ float lsM[2][64];

  const long bq = (long)b*SL*QN;
  const u16* qrow = qkv + (bq + (long)(w*16 + fr)*QN) + h*HD;   // q rows 0..63
  s8v aq[2];
  aq[0] = *(const s8v*)(qrow + fq*8);
  aq[1] = *(const s8v*)(qrow + 32 + fq*8);

  s8v ones_bf;
  {
    const short o = (fr == 0) ? (short)0x3F80 : (short)0;
    #pragma unroll
    for (int j=0;j<8;j++) ones_bf[j] = o;
  }

  const u16* kq = qkv + bq + DM + h*HD;
  const u16* vq = qkv + bq + 2*DM + h*HD;
  const float* mrow = mask + b*SL;

  f4v out[4];
  f4v outl = (f4v)0.f;
  #pragma unroll
  for (int n=0;n<4;n++) out[n] = (f4v)0.f;
  float m = -3.0e38f;

  const int k2 = lane & 31, dq = lane >> 5;
  const int dd0 = w*8 + dq*4;

  us4 va0, vb0, va1, vb1;
  auto stage_issue = [&](int i, int vbuf){
    const int k0 = ck*128 + i*64;
    if (t < 64) lsM[vbuf][t] = mrow[k0 + t];
    #pragma unroll
    for (int j=0;j<2;j++){
      const int r = (w*2+j)*8 + (lane>>3);
      const int d = ((lane&7) ^ (lane>>3))*8;
      __builtin_amdgcn_global_load_lds(
        (const __attribute__((address_space(1))) void*)(kq + (long)(k0+r)*QN + d),
        (__attribute__((address_space(3))) void*)(&lsK[(w*2+j)*512]), 16, 0, 0);
    }
    const u16* v0 = vq + (long)(k0+2*k2)*QN;
    const u16* v1 = vq + (long)(k0+2*k2+1)*QN;
    va0 = *(const us4*)(v0 + dd0);
    vb0 = *(const us4*)(v1 + dd0);
    va1 = *(const us4*)(v0 + dd0 + 32);
    vb1 = *(const us4*)(v1 + dd0 + 32);
  };

  stage_issue(0, 0);
  int cur = 0;
  for (int i = 0; i < 2; i++){
    #pragma unroll
    for (int j=0;j<4;j++){
      const u32 pk0 = (u32)va0[j] | ((u32)vb0[j] << 16);
      *(u32*)&lsVT[cur][(dd0+j)*72 + 2*k2] = pk0;
      const u32 pk1 = (u32)va1[j] | ((u32)vb1[j] << 16);
      *(u32*)&lsVT[cur][(dd0+32+j)*72 + 2*k2] = pk1;
    }
    __syncthreads();                      // bar_a

    f4v s[4];
    #pragma unroll
    for (int n=0;n<4;n++) s[n] = (f4v)0.f;
    #pragma unroll
    for (int kk=0;kk<2;kk++){
      #pragma unroll
      for (int n=0;n<4;n++){
        s8v bf = *(const s8v*)&lsK[(16*n+fr)*64 + (((kk*4+fq) ^ (fr&7))<<3)];
        s[n] = __builtin_amdgcn_mfma_f32_16x16x32_bf16(aq[kk], bf, s[n], 0,0,0);
      }
    }
    __syncthreads();                      // bar_b
    if (i+1 < 2) stage_issue(i+1, cur^1);

    const bool fullOK = __all(lsM[cur][lane] > 0.f);
    if (!fullOK){
      #pragma unroll
      for (int n=0;n<4;n++){
        const float mk = lsM[cur][16*n + fr];
        #pragma unroll
        for (int r=0;r<4;r++)
          s[n][r] = (mk > 0.f) ? s[n][r] : NEGS;
      }
    }
    float rmloc = fmaxf(fmaxf(fmaxf(s[0][0],s[0][1]),fmaxf(s[0][2],s[0][3])),
                        fmaxf(fmaxf(s[1][0],s[1][1]),fmaxf(s[1][2],s[1][3])));
    rmloc = fmaxf(rmloc, fmaxf(fmaxf(fmaxf(s[2][0],s[2][1]),fmaxf(s[2][2],s[2][3])),
                               fmaxf(fmaxf(s[3][0],s[3][1]),fmaxf(s[3][2],s[3][3]))));
    if (__any(rmloc > m + DEFER)){
      float rm = rmloc;
      rm = fmaxf(rm, __shfl_xor(rm, 1, 64));
      rm = fmaxf(rm, __shfl_xor(rm, 2, 64));
      rm = fmaxf(rm, __shfl_xor(rm, 4, 64));
      rm = fmaxf(rm, __shfl_xor(rm, 8, 64));
      const float mn = fmaxf(m, rm);
      const float sf = exp2f((m - mn)*FOLD);
      m = mn;
      outl *= sf;
      #pragma unroll
      for (int n=0;n<4;n++)
        #pragma unroll
        for (int r=0;r<4;r++) out[n][r] *= sf;
    }
    const float mF = m * FOLD;
    u16* lsPw = lsP[w];
    #pragma unroll
    for (int r=0;r<4;r++){
      const float p0 = exp2f(fmaf(s[0][r], FOLD, -mF));
      const float p1 = exp2f(fmaf(s[1][r], FOLD, -mF));
      const float p2 = exp2f(fmaf(s[2][r], FOLD, -mF));
      const float p3 = exp2f(fmaf(s[3][r], FOLD, -mF));
      u32 a, c;
      asm("v_cvt_pk_bf16_f32 %0, %1, %2" : "=v"(a) : "v"(p0), "v"(p1));
      asm("v_cvt_pk_bf16_f32 %0, %1, %2" : "=v"(c) : "v"(p2), "v"(p3));
      const int row = (fq*4+r)*72;
      lsPw[row + fr]      = (u16)a;
      lsPw[row + 16 + fr] = (u16)(a >> 16);
      lsPw[row + 32 + fr] = (u16)c;
      lsPw[row + 48 + fr] = (u16)(c >> 16);
    }
    s8v ap[2];
    ap[0] = *(const s8v*)&lsPw[fr*72 + fq*8];
    ap[1] = *(const s8v*)&lsPw[fr*72 + 32 + fq*8];
    #pragma unroll
    for (int kk=0;kk<2;kk++){
      #pragma unroll
      for (int n=0;n<4;n++){
        s8v bv = *(const s8v*)&lsVT[cur][(16*n+fr)*72 + kk*32 + fq*8];
        out[n] = __builtin_amdgcn_mfma_f32_16x16x32_bf16(ap[kk], bv, out[n], 0,0,0);
      }
      outl = __builtin_amdgcn_mfma_f32_16x16x32_bf16(ap[kk], ones_bf, outl, 0,0,0);
    }
    cur ^= 1;
  }
  float* pob = pout + ((long)(ck*BC*NH + bh))*64*64;
  #pragma unroll
  for (int n=0;n<4;n++)
    #pragma unroll
    for (int r=0;r<4;r++)
      pob[(w*16 + fq*4 + r)*64 + 16*n + fr] = out[n][r];
  if (fr == 0){
    float* pmb = pml + ((long)(ck*BC*NH + bh))*128;
    #pragma unroll
    for (int r=0;r<4;r++){
      pmb[(w*16 + fq*4 + r)*2 + 0] = m * FOLD;      // log2-domain max
      pmb[(w*16 + fq*4 + r)*2 + 1] = outl[r];       // l (reg-ones MFMA column)
    }
  }
}

__global__ __launch_bounds__(256, 2)
void attn_global_combine(const float* __restrict__ pout, const float* __restrict__ pml,
                         u16* __restrict__ ctx)
{
  const int bh = blockIdx.x;
  const int b = bh / NH, h = bh % NH;
  const int t = threadIdx.x;
  __shared__ float wgt[KCH][64];
  __shared__ float rl[64];
  if (t < 64){
    float mc[KCH], lc[KCH];
    #pragma unroll
    for (int c = 0; c < KCH; c++){
      const float* pmb = pml + ((long)(c*BC*NH + bh))*128 + t*2;
      mc[c] = pmb[0]; lc[c] = pmb[1];
    }
    float M = mc[0];
    #pragma unroll
    for (int c = 1; c < KCH; c++) M = fmaxf(M, mc[c]);
    float L = 0.f;
    #pragma unroll
    for (int c = 0; c < KCH; c++){
      const float wv = exp2f(mc[c] - M);
      wgt[c][t] = wv;
      L += lc[c]*wv;
    }
    rl[t] = 1.f/L;
  }
  __syncthreads();
  const int row = t >> 2, dseg = t & 3;
  float acc[16];
  #pragma unroll
  for (int i=0;i<16;i++) acc[i] = 0.f;
  for (int c = 0; c < KCH; c++){
    const float wv = wgt[c][row];
    const float4* pb = (const float4*)(pout + ((long)(c*BC*NH + bh)*64 + row)*64 + dseg*16);
    #pragma unroll
    for (int i = 0; i < 4; i++){
      float4 v = pb[i];
      acc[i*4+0] += v.x*wv; acc[i*4+1] += v.y*wv;
      acc[i*4+2] += v.z*wv; acc[i*4+3] += v.w*wv;
    }
  }
  u16* cr = ctx + ((long)(b*SL + row))*DM + h*HD + dseg*16;
  const float r = rl[row];
  #pragma unroll
  for (int i = 0; i < 16; i += 2){
    u32 pk = (u32)f2b(acc[i]*r) | ((u32)f2b(acc[i+1]*r) << 16);
    *(u32*)(cr + i) = pk;
  }
}

// ---------------------------------------------------------------- LayerNorm + ans/span heads (bf16 h input)
__global__ __launch_bounds__(384, 2)
void ln_heads(const u16* __restrict__ hb, const float* __restrict__ gamma, const float* __restrict__ beta,
              const float* __restrict__ Wa, const float* __restrict__ ba,
              const float* __restrict__ Wsp, const float* __restrict__ bsp,
              float* __restrict__ hn, float* __restrict__ ans, float* __restrict__ span)
{
  const int r = blockIdx.x;
  const int t = threadIdx.x, lane = t & 63, w = t >> 6;   // w in 0..5
  __shared__ float red[12];
  __shared__ float dred[6][5];
  const u32 pk = ((const u32*)(hb + (long)r*DM))[t];
  const float v0 = b2f((u16)(pk & 0xffff));
  const float v1 = b2f((u16)(pk >> 16));
  float sum = wredsum(v0 + v1);
  float sq  = wredsum(v0*v0 + v1*v1);
  if (lane == 0){ red[w] = sum; red[6+w] = sq; }
  __syncthreads();
  float mu = 0.f, msq = 0.f;
  #pragma unroll
  for (int i=0;i<6;i++){ mu += red[i]; msq += red[6+i]; }
  mu *= (1.f/768.f); msq *= (1.f/768.f);
  const float rstd = rsqrtf(msq - mu*mu + 1e-5f);
  const int i0 = 2*t, i1 = 2*t+1;
  const float y0 = (v0 - mu)*rstd*gamma[i0] + beta[i0];
  const float y1 = (v1 - mu)*rstd*gamma[i1] + beta[i1];
  ((float2*)(hn + (long)r*DM))[t] = make_float2(y0, y1);
  float pa0 = y0*Wa[i0*3+0] + y1*Wa[i1*3+0];
  float pa1 = y0*Wa[i0*3+1] + y1*Wa[i1*3+1];
  float pa2 = y0*Wa[i0*3+2] + y1*Wa[i1*3+2];
  float ps0 = y0*Wsp[i0*2+0] + y1*Wsp[i1*2+0];
  float ps1 = y0*Wsp[i0*2+1] + y1*Wsp[i1*2+1];
  pa0 = wredsum(pa0); pa1 = wredsum(pa1); pa2 = wredsum(pa2);
  ps0 = wredsum(ps0); ps1 = wredsum(ps1);
  if (lane == 0){ dred[w][0]=pa0; dred[w][1]=pa1; dred[w][2]=pa2; dred[w][3]=ps0; dred[w][4]=ps1; }
  __syncthreads();
  if (t == 0){
    float A0=0,A1=0,A2=0,S0=0,S1=0;
    #pragma unroll
    for (int i=0;i<6;i++){ A0+=dred[i][0]; A1+=dred[i][1]; A2+=dred[i][2]; S0+=dred[i][3]; S1+=dred[i][4]; }
    ans[(long)r*3+0]  = sigf(A0 + ba[0]);
    ans[(long)r*3+1]  = sigf(A1 + ba[1]);
    ans[(long)r*3+2]  = sigf(A2 + ba[2]);
    span[(long)r*2+0] = sigf(S0 + bsp[0]);
    span[(long)r*2+1] = sigf(S1 + bsp[1]);
  }
}

// ---------------------------------------------------------------- launch
extern "C" void kernel_launch(void* const* d_in, const int* in_sizes, int n_in,
                              void* d_out, int out_size, void* d_ws, size_t ws_size,
                              hipStream_t stream)
{
  const int*   input_ids = (const int*)  d_in[0];
  const float* attn_mask = (const float*)d_in[1];
  const int*   html_idx  = (const int*)  d_in[2];
  const float* embed     = (const float*)d_in[3];
  const float* Wq = (const float*)d_in[4];  const float* bq = (const float*)d_in[5];
  const float* Wk = (const float*)d_in[6];  const float* bk = (const float*)d_in[7];
  const float* Wv = (const float*)d_in[8];  const float* bv = (const float*)d_in[9];
  const float* Wo = (const float*)d_in[10]; const float* bo = (const float*)d_in[11];
  const float* gamma = (const float*)d_in[12]; const float* beta = (const float*)d_in[13];
  const float* Wp = (const float*)d_in[14]; const float* bp = (const float*)d_in[15];
  const float* Wa = (const float*)d_in[16]; const float* ba = (const float*)d_in[17];
  const float* Wsp = (const float*)d_in[18]; const float* bsp = (const float*)d_in[19];

  char* ws = (char*)d_ws;
  size_t off = 0;
  auto take = [&](size_t bytes)->char*{
    char* p = ws + off; off += (bytes + 255) & ~(size_t)255; return p;
  };
  u16*   x_b    = (u16*)  take((size_t)8192*768*2);
  u16*   wt_qkv = (u16*)  take((size_t)2304*768*2);
  u16*   wt_o   = (u16*)  take((size_t)768*768*2);
  u16*   wt_p   = (u16*)  take((size_t)768*768*2);
  float* b_qkv  = (float*)take(2304*4);
  u16*   qkv_b  = (u16*)  take((size_t)8192*2304*2);
  u16*   ctx_b  = (u16*)  take((size_t)8192*768*2);
  u16*   h_b    = (u16*)  take((size_t)8192*768*2);
  u16*   hr_b   = (u16*)  take((size_t)512*768*2);
  u16*   t_b    = (u16*)  take((size_t)512*768*2);
  float* pout   = (float*)take((size_t)KCH*BC*NH*64*64*4);
  float* pml    = (float*)take((size_t)KCH*BC*NH*128*4);

  float* out_hn   = (float*)d_out;
  float* out_ans  = out_hn  + (size_t)8192*768;
  float* out_span = out_ans + (size_t)8192*3;
  float* out_cond = out_span + (size_t)8192*2;

  pack_embed<<<6864, 256, 0, stream>>>(Wq, Wk, Wv, Wo, Wp, bq, bk, bv,
                                       wt_qkv, wt_o, wt_p, b_qkv,
                                       input_ids, embed, x_b);

  gemm_bt<0,true><<<dim3(18,64,1), 256, 0, stream>>>(x_b, wt_qkv, b_qkv, nullptr,
                                                nullptr, qkv_b, 8192, 2304, 768, 0,0,0);
  attn_band_mfma<<<dim3(63,12,2), 256, 0, stream>>>(qkv_b, attn_mask, ctx_b);
  attn_global_part<<<dim3(KCH,12,2), 256, 0, stream>>>(qkv_b, attn_mask, pout, pml);
  attn_global_combine<<<BC*NH, 256, 0, stream>>>(pout, pml, ctx_b);
  gemm_bt<1,true><<<dim3(6,64,1), 256, 0, stream>>>(ctx_b, wt_o, bo, x_b,
                                               nullptr, h_b, 8192, 768, 768, 0,0,0);
  ln_heads<<<8192, 384, 0, stream>>>(h_b, gamma, beta, Wa, ba, Wsp, bsp,
                                     out_hn, out_ans, out_span);
  gather_hr<<<1536, 256, 0, stream>>>(html_idx, out_hn, hr_b);
  gemm_bt<2,false><<<dim3(6,4,1), 256, 0, stream>>>(hr_b, wt_p, bp, nullptr,
                                              nullptr, t_b, 512, 768, 768, 0,0,0);
  gemm_bt<3,false><<<dim3(2,2,2), 256, 0, stream>>>(t_b, hr_b, nullptr, nullptr,
                                              out_cond, nullptr, 256, 256, 768,
                                              (long)256*768, (long)256*768, (long)256*256);
}

// Round 12
// 219.233 us; speedup vs baseline: 1.0322x; 1.0188x over previous
//
#include <hip/hip_runtime.h>

typedef unsigned short u16;
typedef unsigned int   u32;
typedef unsigned long long u64;
typedef __attribute__((ext_vector_type(8))) short s8v;           // MFMA bf16 frag (8 bf16)
typedef __attribute__((ext_vector_type(8))) unsigned short us8;  // raw bf16x8 load
typedef __attribute__((ext_vector_type(4))) unsigned short us4;  // raw bf16x4 load
typedef __attribute__((ext_vector_type(4))) float f4v;           // MFMA acc frag

constexpr int BC  = 2;
constexpr int SL  = 4096;
constexpr int NH  = 12;
constexpr int HD  = 64;
constexpr int DM  = 768;
constexpr int WIN = 256;
constexpr int GLB = 64;
constexpr int QN  = 2304;   // q|k|v packed columns
constexpr int KCH = 32;     // global-attn key chunks (128 keys each)
constexpr int NBQ = 63;     // band q-tiles (q0=64..4032)
constexpr float FOLD = 0.125f * 1.44269504088896f; // scale(1/sqrt(64)) * log2(e)
constexpr float NEGS = -1.0e9f;
constexpr float DEFER = 44.36f;                    // 8 / FOLD (defer-max threshold, raw units)

__device__ __forceinline__ float b2f(u16 b){ return __uint_as_float(((u32)b) << 16); }
__device__ __forceinline__ u16 f2b(float f){
  u32 u = __float_as_uint(f);
  return (u16)((u + 0x7fffu + ((u >> 16) & 1u)) >> 16);  // RNE
}
__device__ __forceinline__ float wredsum(float v){
  #pragma unroll
  for (int o = 32; o > 0; o >>= 1) v += __shfl_xor(v, o, 64);
  return v;
}
__device__ __forceinline__ float sigf(float x){ return 1.f / (1.f + __expf(-x)); }

// ---------------------------------------------------------------- fused weight pack + embed gather
__global__ void pack_embed(const float* __restrict__ Wq, const float* __restrict__ Wk,
                           const float* __restrict__ Wv, const float* __restrict__ Wo,
                           const float* __restrict__ Wp,
                           const float* __restrict__ bq, const float* __restrict__ bk,
                           const float* __restrict__ bv,
                           u16* __restrict__ wt_qkv, u16* __restrict__ wt_o,
                           u16* __restrict__ wt_p, float* __restrict__ b_qkv,
                           const int* __restrict__ ids, const float* __restrict__ emb,
                           u16* __restrict__ xb)
{
  __shared__ float tile[64][65];
  const int bid = blockIdx.x;
  const int t = threadIdx.x;
  if (bid < 720){
    const int mi = bid / 144, rest = bid % 144;
    const int kt = rest / 12, ntc = rest % 12;
    const float* src = (mi==0)?Wq:(mi==1)?Wk:(mi==2)?Wv:(mi==3)?Wo:Wp;
    u16* dst = (mi<3) ? (wt_qkv + (size_t)mi*768*768) : ((mi==3) ? wt_o : wt_p);
    const int k0 = kt*64, n0 = ntc*64;
    #pragma unroll
    for (int i=0;i<4;i++){
      const int r = (t>>4) + i*16;
      float4 v = ((const float4*)(src + (long)(k0+r)*768 + n0))[t&15];
      tile[r][(t&15)*4+0] = v.x; tile[r][(t&15)*4+1] = v.y;
      tile[r][(t&15)*4+2] = v.z; tile[r][(t&15)*4+3] = v.w;
    }
    __syncthreads();
    const int n = t & 63, kc = (t>>6)*16;
    u32* d32 = (u32*)(dst + (long)(n0+n)*768 + k0 + kc);
    #pragma unroll
    for (int i=0;i<8;i++){
      d32[i] = (u32)f2b(tile[kc+2*i][n]) | ((u32)f2b(tile[kc+2*i+1][n]) << 16);
    }
    if (bid < 9){
      const int i = bid*256 + t;
      if (i < 2304) b_qkv[i] = (i < 768) ? bq[i] : (i < 1536) ? bk[i-768] : bv[i-1536];
    }
  } else {
    int e4 = (bid-720)*256 + t;                  // 8192 rows * 192 float4
    int row = e4 / 192, d4 = e4 - row*192;
    int id = ids[row];
    float4 v = ((const float4*)(emb + (long)id*768))[d4];
    u32 p0 = (u32)f2b(v.x) | ((u32)f2b(v.y) << 16);
    u32 p1 = (u32)f2b(v.z) | ((u32)f2b(v.w) << 16);
    ((u32*)(xb + (long)row*768))[d4*2]   = p0;
    ((u32*)(xb + (long)row*768))[d4*2+1] = p1;
  }
}

__global__ void gather_hr(const int* __restrict__ hidx, const float* __restrict__ hn,
                          u16* __restrict__ hrb){
  int e = blockIdx.x*256 + threadIdx.x;          // 512 rows * 768
  if (e >= 512*768) return;
  int r = e / 768, d = e - r*768;
  int b = r >> 8;
  int idx = hidx[r];
  hrb[e] = f2b(hn[((long)(b*SL + idx))*768 + d]);
}

// ---------------------------------------------------------------- bf16 MFMA GEMM
template<int MODE, bool SWZ>
__global__ __launch_bounds__(256, 2)
void gemm_bt(const u16* __restrict__ A, const u16* __restrict__ Bt,
             const float* __restrict__ bias, const u16* __restrict__ resB,
             float* __restrict__ outF, u16* __restrict__ outB,
             int M, int N, int K, long sA, long sB, long sO)
{
  const int bz = blockIdx.z;
  A  += (long)bz * sA;
  Bt += (long)bz * sB;
  int vid = blockIdx.x + gridDim.x*blockIdx.y;
  if constexpr (SWZ){
    const int chunk = (gridDim.x*gridDim.y) >> 3;
    vid = (vid & 7)*chunk + (vid >> 3);
  }
  const int n0 = (vid % gridDim.x) * 128;
  const int m0 = (vid / gridDim.x) * 128;
  __shared__ u16 lsA[128*64];
  __shared__ u16 lsB[128*64];
  const int t = threadIdx.x;
  const int w = t >> 6, lane = t & 63;
  const int wr = w >> 1, wc = w & 1;
  const int fr = lane & 15, fq = lane >> 4;

  f4v acc[4][4];
  #pragma unroll
  for (int i=0;i<4;i++)
    #pragma unroll
    for (int j=0;j<4;j++) acc[i][j] = (f4v)0.f;

  for (int k0 = 0; k0 < K; k0 += 64){
    #pragma unroll
    for (int i=0;i<4;i++){
      int e = (w*4+i)*512 + lane*8;
      int row = e >> 6, col = e & 63;
      __builtin_amdgcn_global_load_lds(
        (const __attribute__((address_space(1))) void*)(A + (long)(m0+row)*K + (k0+col)),
        (__attribute__((address_space(3))) void*)(&lsA[(w*4+i)*512]), 16, 0, 0);
      __builtin_amdgcn_global_load_lds(
        (const __attribute__((address_space(1))) void*)(Bt + (long)(n0+row)*K + (k0+col)),
        (__attribute__((address_space(3))) void*)(&lsB[(w*4+i)*512]), 16, 0, 0);
    }
    __syncthreads();
    #pragma unroll
    for (int kk = 0; kk < 2; kk++){
      s8v af[4], bfv[4];
      #pragma unroll
      for (int mi=0;mi<4;mi++)
        af[mi] = *(const s8v*)&lsA[(wr*64 + mi*16 + fr)*64 + kk*32 + fq*8];
      #pragma unroll
      for (int ni=0;ni<4;ni++)
        bfv[ni] = *(const s8v*)&lsB[(wc*64 + ni*16 + fr)*64 + kk*32 + fq*8];
      #pragma unroll
      for (int mi=0;mi<4;mi++)
        #pragma unroll
        for (int ni=0;ni<4;ni++)
          acc[mi][ni] = __builtin_amdgcn_mfma_f32_16x16x32_bf16(af[mi], bfv[ni], acc[mi][ni], 0, 0, 0);
    }
    __syncthreads();
  }
  #pragma unroll
  for (int mi=0;mi<4;mi++){
    #pragma unroll
    for (int ni=0;ni<4;ni++){
      #pragma unroll
      for (int r=0;r<4;r++){
        int row = m0 + wr*64 + mi*16 + fq*4 + r;
        int col = n0 + wc*64 + ni*16 + fr;
        float v = acc[mi][ni][r];
        if constexpr (MODE == 0){
          v += bias[col];
          outB[(long)row*N + col] = f2b(v);
        } else if constexpr (MODE == 1){
          v += bias[col] + b2f(resB[(long)row*N + col]);
          outB[(long)row*N + col] = f2b(v);
        } else if constexpr (MODE == 2){
          v = fmaxf(v + bias[col], 0.f);
          outB[(long)row*N + col] = f2b(v);
        } else {
          (outF + bz*sO)[(long)row*N + col] = sigf(v);
        }
      }
    }
  }
}

// ---------------------------------------------------------------- fused attention (band + global partials)
// Grid (95, H, B), 256 thr, NATURAL block order (R6's swizzle imbalance removed):
//   x <  63: banded flash q-tile q0=(x+1)*64  (R11-proven swapped-QK^T path)
//   x >= 63: global-row partials, 128-key chunk ck=x-63 (R10-proven classic path)
// Short global blocks backfill the band blocks' second occupancy pass; one launch.
// LDS is the union of both paths (35.5 KB -> 4 blocks/CU).
__global__ __launch_bounds__(256, 4)
void attn_fused2(const u16* __restrict__ qkv, const float* __restrict__ mask,
                 u16* __restrict__ ctx, float* __restrict__ pout, float* __restrict__ pml)
{
  const int h = blockIdx.y, b = blockIdx.z;
  const int t = threadIdx.x;
  const int w = t >> 6, lane = t & 63;
  const int fq = lane >> 4, fr = lane & 15;

  __shared__ u16 lsK[64*64];       // single buffer; row r chunk c8 holds K[r][(c8^(r&7))*8..)
  __shared__ u16 lsVT[2][64*72];   // V^T[d][k(-permuted on band path)], row stride 72
  __shared__ u16 lsP[4][16*72];    // global path only
  __shared__ float lsM[2][64];     // global path only

  const long bq = (long)b*SL*QN;
  const u16* kq = qkv + bq + DM + h*HD;
  const u16* vq = qkv + bq + 2*DM + h*HD;
  const float* mrow = mask + b*SL;

  s8v ones_bf;
  {
    const short o = (fr == 0) ? (short)0x3F80 : (short)0;
    #pragma unroll
    for (int j=0;j<8;j++) ones_bf[j] = o;
  }

  f4v out[4];
  f4v outl = (f4v)0.f;
  #pragma unroll
  for (int n=0;n<4;n++) out[n] = (f4v)0.f;
  float m = -3.0e38f;

  const int k2 = lane & 31, dq = lane >> 5;    // V-stage: k-pair, d-quad
  const int dd0 = w*8 + dq*4;

  if (blockIdx.x < NBQ){
    // ===================== banded path (R11 swapped-QK^T, in-register P) =====================
    const int q0 = (blockIdx.x + 1) * 64;
    const u16* qrow = qkv + (bq + (long)(q0 + w*16 + fr)*QN) + h*HD;
    s8v aq[2];
    aq[0] = *(const s8v*)(qrow + fq*8);
    aq[1] = *(const s8v*)(qrow + 32 + fq*8);

    const int ti_lo = (q0 < 320) ? ((320 - q0) >> 6) : 0;
    const int ti_hi_raw = (4352 - q0) >> 6;
    const int ti_hi = ti_hi_raw < 9 ? ti_hi_raw : 9;
    const int NTT = 1 + (ti_hi - ti_lo);
    const int kb0 = q0 - 256 + ti_lo*64;

    // permuted column for k-pair (2*k2, 2*k2+1)
    const int kv = 2*k2;
    const int cperm = (((kv>>4)>>1)<<5) + (((kv>>2)&3)<<3) + (((kv>>4)&1)<<2) + (kv&3);

    us4 va0, vb0, va1, vb1;
    float mval;
    auto stage_issue = [&](int i){
      const int k0 = (i == 0) ? 0 : kb0 + (i-1)*64;
      mval = mrow[k0 + lane];
      #pragma unroll
      for (int j=0;j<2;j++){
        const int r = (w*2+j)*8 + (lane>>3);
        const int d = ((lane&7) ^ (lane>>3))*8;          // pre-swizzled source col
        __builtin_amdgcn_global_load_lds(
          (const __attribute__((address_space(1))) void*)(kq + (long)(k0+r)*QN + d),
          (__attribute__((address_space(3))) void*)(&lsK[(w*2+j)*512]), 16, 0, 0);
      }
      const u16* v0 = vq + (long)(k0+kv)*QN;
      const u16* v1 = vq + (long)(k0+kv+1)*QN;
      va0 = *(const us4*)(v0 + dd0);
      vb0 = *(const us4*)(v1 + dd0);
      va1 = *(const us4*)(v0 + dd0 + 32);
      vb1 = *(const us4*)(v1 + dd0 + 32);
    };

    stage_issue(0);
    int cur = 0;
    for (int i = 0; i < NTT; i++){
      const int k0 = (i == 0) ? 0 : kb0 + (i-1)*64;
      #pragma unroll
      for (int j=0;j<4;j++){
        const u32 pk0 = (u32)va0[j] | ((u32)vb0[j] << 16);
        *(u32*)&lsVT[cur][(dd0+j)*72 + cperm] = pk0;
        const u32 pk1 = (u32)va1[j] | ((u32)vb1[j] << 16);
        *(u32*)&lsVT[cur][(dd0+32+j)*72 + cperm] = pk1;
      }
      __syncthreads();                      // bar_a: K(i) DMA + V(i) visible

      f4v s[4];
      #pragma unroll
      for (int n=0;n<4;n++) s[n] = (f4v)0.f;
      #pragma unroll
      for (int kk=0;kk<2;kk++){
        #pragma unroll
        for (int n=0;n<4;n++){
          s8v bf = *(const s8v*)&lsK[(16*n+fr)*64 + (((kk*4+fq) ^ (fr&7))<<3)];
          s[n] = __builtin_amdgcn_mfma_f32_16x16x32_bf16(bf, aq[kk], s[n], 0,0,0);
        }
      }
      __syncthreads();                      // bar_b: all waves' lsK reads done
      const u64 mkb = __ballot(mval > 0.f);
      if (i+1 < NTT) stage_issue(i+1);

      const bool isg = (i == 0);
      const int dlt = k0 - q0 - w*16;
      const bool fullOK = (~mkb == 0ull) && (isg || (dlt >= -241 && dlt <= 193));
      if (!fullOK){
        const int base = k0 + 4*fq - (q0 + w*16 + fr);
        #pragma unroll
        for (int n=0;n<4;n++){
          #pragma unroll
          for (int r=0;r<4;r++){
            const bool mb = (mkb >> (16*n + 4*fq + r)) & 1ull;
            const int dd = base + 16*n + r;
            const bool valid = mb && (isg || (dd >= -WIN && dd <= WIN));
            s[n][r] = valid ? s[n][r] : NEGS;
          }
        }
      }
      float rmloc = fmaxf(fmaxf(fmaxf(s[0][0],s[0][1]),fmaxf(s[0][2],s[0][3])),
                          fmaxf(fmaxf(s[1][0],s[1][1]),fmaxf(s[1][2],s[1][3])));
      rmloc = fmaxf(rmloc, fmaxf(fmaxf(fmaxf(s[2][0],s[2][1]),fmaxf(s[2][2],s[2][3])),
                                 fmaxf(fmaxf(s[3][0],s[3][1]),fmaxf(s[3][2],s[3][3]))));
      if (__any(rmloc > m + DEFER)){
        float rm = rmloc;
        rm = fmaxf(rm, __shfl_xor(rm, 1, 64));
        rm = fmaxf(rm, __shfl_xor(rm, 2, 64));
        rm = fmaxf(rm, __shfl_xor(rm, 4, 64));
        rm = fmaxf(rm, __shfl_xor(rm, 8, 64));
        rm = fmaxf(rm, __shfl_xor(rm, 16, 64));
        rm = fmaxf(rm, __shfl_xor(rm, 32, 64));
        const float mn = fmaxf(m, rm);
        const float sf = exp2f((m - mn)*FOLD);
        m = mn;
        outl *= sf;
        #pragma unroll
        for (int n=0;n<4;n++)
          #pragma unroll
          for (int r=0;r<4;r++) out[n][r] *= sf;
      }
      const float mF = m * FOLD;
      float p00 = exp2f(fmaf(s[0][0], FOLD, -mF)), p01 = exp2f(fmaf(s[0][1], FOLD, -mF));
      float p02 = exp2f(fmaf(s[0][2], FOLD, -mF)), p03 = exp2f(fmaf(s[0][3], FOLD, -mF));
      float p10 = exp2f(fmaf(s[1][0], FOLD, -mF)), p11 = exp2f(fmaf(s[1][1], FOLD, -mF));
      float p12 = exp2f(fmaf(s[1][2], FOLD, -mF)), p13 = exp2f(fmaf(s[1][3], FOLD, -mF));
      float p20 = exp2f(fmaf(s[2][0], FOLD, -mF)), p21 = exp2f(fmaf(s[2][1], FOLD, -mF));
      float p22 = exp2f(fmaf(s[2][2], FOLD, -mF)), p23 = exp2f(fmaf(s[2][3], FOLD, -mF));
      float p30 = exp2f(fmaf(s[3][0], FOLD, -mF)), p31 = exp2f(fmaf(s[3][1], FOLD, -mF));
      float p32 = exp2f(fmaf(s[3][2], FOLD, -mF)), p33 = exp2f(fmaf(s[3][3], FOLD, -mF));
      u32 c0,c1,c2,c3,c4,c5,c6,c7;
      asm("v_cvt_pk_bf16_f32 %0, %1, %2" : "=v"(c0) : "v"(p00), "v"(p01));
      asm("v_cvt_pk_bf16_f32 %0, %1, %2" : "=v"(c1) : "v"(p02), "v"(p03));
      asm("v_cvt_pk_bf16_f32 %0, %1, %2" : "=v"(c2) : "v"(p10), "v"(p11));
      asm("v_cvt_pk_bf16_f32 %0, %1, %2" : "=v"(c3) : "v"(p12), "v"(p13));
      asm("v_cvt_pk_bf16_f32 %0, %1, %2" : "=v"(c4) : "v"(p20), "v"(p21));
      asm("v_cvt_pk_bf16_f32 %0, %1, %2" : "=v"(c5) : "v"(p22), "v"(p23));
      asm("v_cvt_pk_bf16_f32 %0, %1, %2" : "=v"(c6) : "v"(p30), "v"(p31));
      asm("v_cvt_pk_bf16_f32 %0, %1, %2" : "=v"(c7) : "v"(p32), "v"(p33));
      s8v ap0, ap1;
      { u32* u = (u32*)&ap0; u[0]=c0; u[1]=c1; u[2]=c2; u[3]=c3; }
      { u32* u = (u32*)&ap1; u[0]=c4; u[1]=c5; u[2]=c6; u[3]=c7; }
      #pragma unroll
      for (int n=0;n<4;n++){
        s8v bv0 = *(const s8v*)&lsVT[cur][(16*n+fr)*72 + fq*8];
        out[n] = __builtin_amdgcn_mfma_f32_16x16x32_bf16(ap0, bv0, out[n], 0,0,0);
        s8v bv1 = *(const s8v*)&lsVT[cur][(16*n+fr)*72 + 32 + fq*8];
        out[n] = __builtin_amdgcn_mfma_f32_16x16x32_bf16(ap1, bv1, out[n], 0,0,0);
      }
      outl = __builtin_amdgcn_mfma_f32_16x16x32_bf16(ap0, ones_bf, outl, 0,0,0);
      outl = __builtin_amdgcn_mfma_f32_16x16x32_bf16(ap1, ones_bf, outl, 0,0,0);
      cur ^= 1;
    }
    float linv[4];
    #pragma unroll
    for (int r=0;r<4;r++) linv[r] = 1.f / __shfl(outl[r], lane & 48, 64);
    u16* cb = ctx + (((long)(b*SL) + q0 + w*16 + fq*4))*DM + h*HD + fr;
    #pragma unroll
    for (int n=0;n<4;n++)
      #pragma unroll
      for (int r=0;r<4;r++)
        cb[(long)r*DM + 16*n] = f2b(out[n][r]*linv[r]);

  } else {
    // ===================== global-row partials path (R10-proven) =====================
    const int ck = blockIdx.x - NBQ;
    const int bh = b*NH + h;
    const u16* qrow = qkv + (bq + (long)(w*16 + fr)*QN) + h*HD;   // q rows 0..63
    s8v aq[2];
    aq[0] = *(const s8v*)(qrow + fq*8);
    aq[1] = *(const s8v*)(qrow + 32 + fq*8);

    us4 va0, vb0, va1, vb1;
    auto stage_issue = [&](int i, int vbuf){
      const int k0 = ck*128 + i*64;
      if (t < 64) lsM[vbuf][t] = mrow[k0 + t];
      #pragma unroll
      for (int j=0;j<2;j++){
        const int r = (w*2+j)*8 + (lane>>3);
        const int d = ((lane&7) ^ (lane>>3))*8;
        __builtin_amdgcn_global_load_lds(
          (const __attribute__((address_space(1))) void*)(kq + (long)(k0+r)*QN + d),
          (__attribute__((address_space(3))) void*)(&lsK[(w*2+j)*512]), 16, 0, 0);
      }
      const u16* v0 = vq + (long)(k0+2*k2)*QN;
      const u16* v1 = vq + (long)(k0+2*k2+1)*QN;
      va0 = *(const us4*)(v0 + dd0);
      vb0 = *(const us4*)(v1 + dd0);
      va1 = *(const us4*)(v0 + dd0 + 32);
      vb1 = *(const us4*)(v1 + dd0 + 32);
    };

    stage_issue(0, 0);
    int cur = 0;
    for (int i = 0; i < 2; i++){
      #pragma unroll
      for (int j=0;j<4;j++){
        const u32 pk0 = (u32)va0[j] | ((u32)vb0[j] << 16);
        *(u32*)&lsVT[cur][(dd0+j)*72 + 2*k2] = pk0;
        const u32 pk1 = (u32)va1[j] | ((u32)vb1[j] << 16);
        *(u32*)&lsVT[cur][(dd0+32+j)*72 + 2*k2] = pk1;
      }
      __syncthreads();                      // bar_a

      f4v s[4];
      #pragma unroll
      for (int n=0;n<4;n++) s[n] = (f4v)0.f;
      #pragma unroll
      for (int kk=0;kk<2;kk++){
        #pragma unroll
        for (int n=0;n<4;n++){
          s8v bf = *(const s8v*)&lsK[(16*n+fr)*64 + (((kk*4+fq) ^ (fr&7))<<3)];
          s[n] = __builtin_amdgcn_mfma_f32_16x16x32_bf16(aq[kk], bf, s[n], 0,0,0);
        }
      }
      __syncthreads();                      // bar_b
      if (i+1 < 2) stage_issue(i+1, cur^1);

      const bool fullOK = __all(lsM[cur][lane] > 0.f);
      if (!fullOK){
        #pragma unroll
        for (int n=0;n<4;n++){
          const float mk = lsM[cur][16*n + fr];
          #pragma unroll
          for (int r=0;r<4;r++)
            s[n][r] = (mk > 0.f) ? s[n][r] : NEGS;
        }
      }
      float rmloc = fmaxf(fmaxf(fmaxf(s[0][0],s[0][1]),fmaxf(s[0][2],s[0][3])),
                          fmaxf(fmaxf(s[1][0],s[1][1]),fmaxf(s[1][2],s[1][3])));
      rmloc = fmaxf(rmloc, fmaxf(fmaxf(fmaxf(s[2][0],s[2][1]),fmaxf(s[2][2],s[2][3])),
                                 fmaxf(fmaxf(s[3][0],s[3][1]),fmaxf(s[3][2],s[3][3]))));
      if (__any(rmloc > m + DEFER)){
        float rm = rmloc;
        rm = fmaxf(rm, __shfl_xor(rm, 1, 64));
        rm = fmaxf(rm, __shfl_xor(rm, 2, 64));
        rm = fmaxf(rm, __shfl_xor(rm, 4, 64));
        rm = fmaxf(rm, __shfl_xor(rm, 8, 64));
        const float mn = fmaxf(m, rm);
        const float sf = exp2f((m - mn)*FOLD);
        m = mn;
        outl *= sf;
        #pragma unroll
        for (int n=0;n<4;n++)
          #pragma unroll
          for (int r=0;r<4;r++) out[n][r] *= sf;
      }
      const float mF = m * FOLD;
      u16* lsPw = lsP[w];
      #pragma unroll
      for (int r=0;r<4;r++){
        const float p0 = exp2f(fmaf(s[0][r], FOLD, -mF));
        const float p1 = exp2f(fmaf(s[1][r], FOLD, -mF));
        const float p2 = exp2f(fmaf(s[2][r], FOLD, -mF));
        const float p3 = exp2f(fmaf(s[3][r], FOLD, -mF));
        u32 a, c;
        asm("v_cvt_pk_bf16_f32 %0, %1, %2" : "=v"(a) : "v"(p0), "v"(p1));
        asm("v_cvt_pk_bf16_f32 %0, %1, %2" : "=v"(c) : "v"(p2), "v"(p3));
        const int row = (fq*4+r)*72;
        lsPw[row + fr]      = (u16)a;
        lsPw[row + 16 + fr] = (u16)(a >> 16);
        lsPw[row + 32 + fr] = (u16)c;
        lsPw[row + 48 + fr] = (u16)(c >> 16);
      }
      s8v ap[2];
      ap[0] = *(const s8v*)&lsPw[fr*72 + fq*8];
      ap[1] = *(const s8v*)&lsPw[fr*72 + 32 + fq*8];
      #pragma unroll
      for (int kk=0;kk<2;kk++){
        #pragma unroll
        for (int n=0;n<4;n++){
          s8v bv = *(const s8v*)&lsVT[cur][(16*n+fr)*72 + kk*32 + fq*8];
          out[n] = __builtin_amdgcn_mfma_f32_16x16x32_bf16(ap[kk], bv, out[n], 0,0,0);
        }
        outl = __builtin_amdgcn_mfma_f32_16x16x32_bf16(ap[kk], ones_bf, outl, 0,0,0);
      }
      cur ^= 1;
    }
    float* pob = pout + ((long)(ck*BC*NH + bh))*64*64;
    #pragma unroll
    for (int n=0;n<4;n++)
      #pragma unroll
      for (int r=0;r<4;r++)
        pob[(w*16 + fq*4 + r)*64 + 16*n + fr] = out[n][r];
    if (fr == 0){
      float* pmb = pml + ((long)(ck*BC*NH + bh))*128;
      #pragma unroll
      for (int r=0;r<4;r++){
        pmb[(w*16 + fq*4 + r)*2 + 0] = m * FOLD;      // log2-domain max
        pmb[(w*16 + fq*4 + r)*2 + 1] = outl[r];       // l (reg-ones MFMA column)
      }
    }
  }
}

__global__ __launch_bounds__(256, 2)
void attn_global_combine(const float* __restrict__ pout, const float* __restrict__ pml,
                         u16* __restrict__ ctx)
{
  const int bh = blockIdx.x;
  const int b = bh / NH, h = bh % NH;
  const int t = threadIdx.x;
  __shared__ float wgt[KCH][64];
  __shared__ float rl[64];
  if (t < 64){
    float mc[KCH], lc[KCH];
    #pragma unroll
    for (int c = 0; c < KCH; c++){
      const float* pmb = pml + ((long)(c*BC*NH + bh))*128 + t*2;
      mc[c] = pmb[0]; lc[c] = pmb[1];
    }
    float M = mc[0];
    #pragma unroll
    for (int c = 1; c < KCH; c++) M = fmaxf(M, mc[c]);
    float L = 0.f;
    #pragma unroll
    for (int c = 0; c < KCH; c++){
      const float wv = exp2f(mc[c] - M);
      wgt[c][t] = wv;
      L += lc[c]*wv;
    }
    rl[t] = 1.f/L;
  }
  __syncthreads();
  const int row = t >> 2, dseg = t & 3;
  float acc[16];
  #pragma unroll
  for (int i=0;i<16;i++) acc[i] = 0.f;
  for (int c = 0; c < KCH; c++){
    const float wv = wgt[c][row];
    const float4* pb = (const float4*)(pout + ((long)(c*BC*NH + bh)*64 + row)*64 + dseg*16);
    #pragma unroll
    for (int i = 0; i < 4; i++){
      float4 v = pb[i];
      acc[i*4+0] += v.x*wv; acc[i*4+1] += v.y*wv;
      acc[i*4+2] += v.z*wv; acc[i*4+3] += v.w*wv;
    }
  }
  u16* cr = ctx + ((long)(b*SL + row))*DM + h*HD + dseg*16;
  const float r = rl[row];
  #pragma unroll
  for (int i = 0; i < 16; i += 2){
    u32 pk = (u32)f2b(acc[i]*r) | ((u32)f2b(acc[i+1]*r) << 16);
    *(u32*)(cr + i) = pk;
  }
}

// ---------------------------------------------------------------- LayerNorm + ans/span heads (bf16 h input)
__global__ __launch_bounds__(384, 2)
void ln_heads(const u16* __restrict__ hb, const float* __restrict__ gamma, const float* __restrict__ beta,
              const float* __restrict__ Wa, const float* __restrict__ ba,
              const float* __restrict__ Wsp, const float* __restrict__ bsp,
              float* __restrict__ hn, float* __restrict__ ans, float* __restrict__ span)
{
  const int r = blockIdx.x;
  const int t = threadIdx.x, lane = t & 63, w = t >> 6;   // w in 0..5
  __shared__ float red[12];
  __shared__ float dred[6][5];
  const u32 pk = ((const u32*)(hb + (long)r*DM))[t];
  const float v0 = b2f((u16)(pk & 0xffff));
  const float v1 = b2f((u16)(pk >> 16));
  float sum = wredsum(v0 + v1);
  float sq  = wredsum(v0*v0 + v1*v1);
  if (lane == 0){ red[w] = sum; red[6+w] = sq; }
  __syncthreads();
  float mu = 0.f, msq = 0.f;
  #pragma unroll
  for (int i=0;i<6;i++){ mu += red[i]; msq += red[6+i]; }
  mu *= (1.f/768.f); msq *= (1.f/768.f);
  const float rstd = rsqrtf(msq - mu*mu + 1e-5f);
  const int i0 = 2*t, i1 = 2*t+1;
  const float y0 = (v0 - mu)*rstd*gamma[i0] + beta[i0];
  const float y1 = (v1 - mu)*rstd*gamma[i1] + beta[i1];
  ((float2*)(hn + (long)r*DM))[t] = make_float2(y0, y1);
  float pa0 = y0*Wa[i0*3+0] + y1*Wa[i1*3+0];
  float pa1 = y0*Wa[i0*3+1] + y1*Wa[i1*3+1];
  float pa2 = y0*Wa[i0*3+2] + y1*Wa[i1*3+2];
  float ps0 = y0*Wsp[i0*2+0] + y1*Wsp[i1*2+0];
  float ps1 = y0*Wsp[i0*2+1] + y1*Wsp[i1*2+1];
  pa0 = wredsum(pa0); pa1 = wredsum(pa1); pa2 = wredsum(pa2);
  ps0 = wredsum(ps0); ps1 = wredsum(ps1);
  if (lane == 0){ dred[w][0]=pa0; dred[w][1]=pa1; dred[w][2]=pa2; dred[w][3]=ps0; dred[w][4]=ps1; }
  __syncthreads();
  if (t == 0){
    float A0=0,A1=0,A2=0,S0=0,S1=0;
    #pragma unroll
    for (int i=0;i<6;i++){ A0+=dred[i][0]; A1+=dred[i][1]; A2+=dred[i][2]; S0+=dred[i][3]; S1+=dred[i][4]; }
    ans[(long)r*3+0]  = sigf(A0 + ba[0]);
    ans[(long)r*3+1]  = sigf(A1 + ba[1]);
    ans[(long)r*3+2]  = sigf(A2 + ba[2]);
    span[(long)r*2+0] = sigf(S0 + bsp[0]);
    span[(long)r*2+1] = sigf(S1 + bsp[1]);
  }
}

// ---------------------------------------------------------------- launch
extern "C" void kernel_launch(void* const* d_in, const int* in_sizes, int n_in,
                              void* d_out, int out_size, void* d_ws, size_t ws_size,
                              hipStream_t stream)
{
  const int*   input_ids = (const int*)  d_in[0];
  const float* attn_mask = (const float*)d_in[1];
  const int*   html_idx  = (const int*)  d_in[2];
  const float* embed     = (const float*)d_in[3];
  const float* Wq = (const float*)d_in[4];  const float* bq = (const float*)d_in[5];
  const float* Wk = (const float*)d_in[6];  const float* bk = (const float*)d_in[7];
  const float* Wv = (const float*)d_in[8];  const float* bv = (const float*)d_in[9];
  const float* Wo = (const float*)d_in[10]; const float* bo = (const float*)d_in[11];
  const float* gamma = (const float*)d_in[12]; const float* beta = (const float*)d_in[13];
  const float* Wp = (const float*)d_in[14]; const float* bp = (const float*)d_in[15];
  const float* Wa = (const float*)d_in[16]; const float* ba = (const float*)d_in[17];
  const float* Wsp = (const float*)d_in[18]; const float* bsp = (const float*)d_in[19];

  char* ws = (char*)d_ws;
  size_t off = 0;
  auto take = [&](size_t bytes)->char*{
    char* p = ws + off; off += (bytes + 255) & ~(size_t)255; return p;
  };
  u16*   x_b    = (u16*)  take((size_t)8192*768*2);
  u16*   wt_qkv = (u16*)  take((size_t)2304*768*2);
  u16*   wt_o   = (u16*)  take((size_t)768*768*2);
  u16*   wt_p   = (u16*)  take((size_t)768*768*2);
  float* b_qkv  = (float*)take(2304*4);
  u16*   qkv_b  = (u16*)  take((size_t)8192*2304*2);
  u16*   ctx_b  = (u16*)  take((size_t)8192*768*2);
  u16*   h_b    = (u16*)  take((size_t)8192*768*2);
  u16*   hr_b   = (u16*)  take((size_t)512*768*2);
  u16*   t_b    = (u16*)  take((size_t)512*768*2);
  float* pout   = (float*)take((size_t)KCH*BC*NH*64*64*4);
  float* pml    = (float*)take((size_t)KCH*BC*NH*128*4);

  float* out_hn   = (float*)d_out;
  float* out_ans  = out_hn  + (size_t)8192*768;
  float* out_span = out_ans + (size_t)8192*3;
  float* out_cond = out_span + (size_t)8192*2;

  pack_embed<<<6864, 256, 0, stream>>>(Wq, Wk, Wv, Wo, Wp, bq, bk, bv,
                                       wt_qkv, wt_o, wt_p, b_qkv,
                                       input_ids, embed, x_b);

  gemm_bt<0,true><<<dim3(18,64,1), 256, 0, stream>>>(x_b, wt_qkv, b_qkv, nullptr,
                                                nullptr, qkv_b, 8192, 2304, 768, 0,0,0);
  attn_fused2<<<dim3(NBQ + KCH, 12, 2), 256, 0, stream>>>(qkv_b, attn_mask, ctx_b, pout, pml);
  attn_global_combine<<<BC*NH, 256, 0, stream>>>(pout, pml, ctx_b);
  gemm_bt<1,true><<<dim3(6,64,1), 256, 0, stream>>>(ctx_b, wt_o, bo, x_b,
                                               nullptr, h_b, 8192, 768, 768, 0,0,0);
  ln_heads<<<8192, 384, 0, stream>>>(h_b, gamma, beta, Wa, ba, Wsp, bsp,
                                     out_hn, out_ans, out_span);
  gather_hr<<<1536, 256, 0, stream>>>(html_idx, out_hn, hr_b);
  gemm_bt<2,false><<<dim3(6,4,1), 256, 0, stream>>>(hr_b, wt_p, bp, nullptr,
                                              nullptr, t_b, 512, 768, 768, 0,0,0);
  gemm_bt<3,false><<<dim3(2,2,2), 256, 0, stream>>>(t_b, hr_b, nullptr, nullptr,
                                              out_cond, nullptr, 256, 256, 768,
                                              (long)256*768, (long)256*768, (long)256*256);
}